// Round 15
// baseline (2643.237 us; speedup 1.0000x reference)
//
#include <hip/hip_runtime.h>
#include <hip/hip_bf16.h>
#include <math.h>

// Problem constants
#define BB 64
#define SS 256
#define DD 1024
#define HH 16
#define FFN 4096
#define GHH 100
#define NCC 7
#define LL 4
#define TT (BB*SS)          // 16384 tokens
#define DHH 64

typedef unsigned short u16;
typedef unsigned int u32;
typedef __attribute__((ext_vector_type(4))) float f32x4;
typedef __attribute__((ext_vector_type(8))) short s16x8;
typedef __attribute__((ext_vector_type(4))) unsigned short u16x4;
typedef __attribute__((ext_vector_type(8))) unsigned short u16x8;

__device__ __forceinline__ u16 f2bf(float f) {
  union { float f; u32 u; } x; x.f = f;
  u32 r = x.u + 0x7FFFu + ((x.u >> 16) & 1u);
  return (u16)(r >> 16);
}
__device__ __forceinline__ float bf2f(u16 b) {
  union { u32 u; float f; } x; x.u = ((u32)b) << 16;
  return x.f;
}
__device__ __forceinline__ u32 pkbf(float a, float b) {
  return (u32)f2bf(a) | ((u32)f2bf(b) << 16);
}
__device__ __forceinline__ float lo16(u32 u) {
  union { u32 u; float f; } x; x.u = u << 16; return x.f;
}
__device__ __forceinline__ float hi16(u32 u) {
  union { u32 u; float f; } x; x.u = u & 0xffff0000u; return x.f;
}

// ---------------- fused fp32 -> bf16 convert (4 tensors) ----------------
__global__ void k_f2bf4(const float* __restrict__ s0, u16* __restrict__ d0, int n0,
                        const float* __restrict__ s1, u16* __restrict__ d1, int n1,
                        const float* __restrict__ s2, u16* __restrict__ d2, int n2,
                        const float* __restrict__ s3, u16* __restrict__ d3, int n3) {
  int stride = gridDim.x * blockDim.x;
  int total = n0 + n1 + n2 + n3;
  for (int i = blockIdx.x * blockDim.x + threadIdx.x; i < total; i += stride) {
    const float* s; u16* d; int j = i;
    if (j < n0) { s = s0; d = d0; }
    else {
      j -= n0;
      if (j < n1) { s = s1; d = d1; }
      else {
        j -= n1;
        if (j < n2) { s = s2; d = d2; }
        else { j -= n2; s = s3; d = d3; }
      }
    }
    f32x4 v = *(const f32x4*)(s + (size_t)j * 4);
    u16x4 o;
    o[0] = f2bf(v[0]); o[1] = f2bf(v[1]); o[2] = f2bf(v[2]); o[3] = f2bf(v[3]);
    *(u16x4*)(d + (size_t)j * 4) = o;
  }
}

// ---------------- positional encoding ----------------
__global__ void k_pe(float* __restrict__ pe) {
  int i = blockIdx.x * blockDim.x + threadIdx.x;     // over S*D/2
  if (i >= SS * DD / 2) return;
  int s = i / (DD / 2), j = i % (DD / 2);
  float div = __expf((float)(2 * j) * (-9.210340371976184f / (float)DD));
  float a = (float)s * div;
  pe[s * DD + 2 * j]     = sinf(a);
  pe[s * DD + 2 * j + 1] = cosf(a);
}

// ---------------- embedding + PE (single bf16 stream) ----------------
__global__ void k_embed(const int* __restrict__ src, const float* __restrict__ emb,
                        const float* __restrict__ pe, u16* __restrict__ xb) {
  int i = blockIdx.x * blockDim.x + threadIdx.x;     // over T*D/4
  if (i >= TT * DD / 4) return;
  int t = i / (DD / 4);
  int d4 = (i % (DD / 4)) * 4;
  int s = t % SS;
  int tok = src[t];
  f32x4 e = *(const f32x4*)(emb + (size_t)tok * DD + d4);
  f32x4 p = *(const f32x4*)(pe + (size_t)s * DD + d4);
  u16x4 o;
  o[0] = f2bf(e[0] * 32.0f + p[0]); o[1] = f2bf(e[1] * 32.0f + p[1]);
  o[2] = f2bf(e[2] * 32.0f + p[2]); o[3] = f2bf(e[3] * 32.0f + p[3]);
  *(u16x4*)(xb + (size_t)t * DD + d4) = o;
}

// ---------------- GRU body (R10-proven; device fn for fusion) --------------
#define F7(X) X(0) X(1) X(2) X(3) X(4) X(5) X(6)
#define C12(X) X(0) X(1) X(2) X(3) X(4) X(5) X(6) X(7) X(8) X(9) X(10) X(11)

__device__ __forceinline__
void gru_body(const float* __restrict__ em, const float* __restrict__ Wih,
              const float* __restrict__ bih, const float* __restrict__ Whh,
              const float* __restrict__ bhh, float* __restrict__ emo, int b) {
  const int tid = threadIdx.x;
  const int iraw = tid / 6;
  const int sub = tid - iraw * 6;
  const int g = sub >> 1, half = sub & 1;
  const bool act = iraw < 100;
  const int i = act ? iraw : 99;
  const int grow = g * 100 + i;

  __shared__ __align__(16) float h[2][104];
  __shared__ float vals[400];
  __shared__ __align__(16) float emL[SS][8];
  __shared__ float emoL[16][100];

  const float* rowP = Whh + (size_t)grow * 100 + half * 50;
#define LW(q) u32 wa##q = pkbf(rowP[4*(q)], rowP[4*(q)+1]); \
              u32 wb##q = pkbf(rowP[4*(q)+2], rowP[4*(q)+3]); \
              asm volatile("" : "+v"(wa##q), "+v"(wb##q));
  C12(LW)
#undef LW
  u32 wt = pkbf(rowP[48], rowP[49]);
  asm volatile("" : "+v"(wt));

#define LI(f) float wi##f = Wih[grow * 7 + (f)];
  F7(LI)
#undef LI
  const float bhhv = bhh[grow];
  const float bihv = bih[grow];

  {
    const float* ebase = em + (size_t)b * SS * 7;
    for (int idx = tid; idx < SS * 7; idx += 640) {
      int ss = idx / 7, ff = idx - ss * 7;
      emL[ss][ff] = ebase[idx];
    }
  }
  if (tid < 104) { h[0][tid] = 0.f; h[1][tid] = 0.f; }
  __syncthreads();

  for (int s = 0; s < SS; ++s) {
    const float* hc = h[s & 1];
    float* hb_next = h[(s & 1) ^ 1];
    float xp = bihv;
#define MI(f) xp += wi##f * emL[s][f];
    F7(MI)
#undef MI
    const float* hbp = hc + half * 52;
    float a0 = 0.f, a1 = 0.f, a2 = 0.f, a3 = 0.f;
#define MC(q) { f32x4 hv = *(const f32x4*)(hbp + 4*(q)); \
    a0 += lo16(wa##q) * hv[0]; a1 += hi16(wa##q) * hv[1]; \
    a2 += lo16(wb##q) * hv[2]; a3 += hi16(wb##q) * hv[3]; }
    C12(MC)
#undef MC
    { a0 += lo16(wt) * hbp[48]; a1 += hi16(wt) * hbp[49]; }
    float a = (a0 + a1) + (a2 + a3);
    a += __shfl_xor(a, 1);
    if (act && half == 0) {
      if (g == 2) { vals[200 + i] = xp; vals[300 + i] = a + bhhv; }
      else        { vals[g * 100 + i] = xp + a + bhhv; }
    }
    __syncthreads();
    if (tid < 100) {
      int slot = tid + (tid >= 50 ? 2 : 0);
      float hold = hc[slot];
      float rr = 1.f / (1.f + __expf(-vals[tid]));
      float zz = 1.f / (1.f + __expf(-vals[100 + tid]));
      float nx = vals[200 + tid] + rr * vals[300 + tid];
      float e2 = __expf(-2.f * fabsf(nx));
      float th = (1.f - e2) / (1.f + e2);
      float nn = copysignf(th, nx);
      float hv = (1.f - zz) * nn + zz * hold;
      hb_next[slot] = hv;
      emoL[s & 15][tid] = hv;
    }
    __syncthreads();
    if ((s & 15) == 15) {
      float* dst = emo + ((size_t)b * SS + (s - 15)) * GHH;
      for (int idx = tid; idx < 16 * GHH; idx += 640)
        dst[idx] = (&emoL[0][0])[idx];
    }
  }
}

// ---------------- 256x256 8-phase GEMM (T1+T2+T3+T4+T5) ----------------
#define MEMF asm volatile("" ::: "memory")
#define GBAR do { MEMF; __builtin_amdgcn_sched_barrier(0); __builtin_amdgcn_s_barrier(); __builtin_amdgcn_sched_barrier(0); MEMF; } while(0)
#define VMW4 asm volatile("s_waitcnt vmcnt(4)" ::: "memory")

#define STG(P, isB, h, l, buf, kt) \
  __builtin_amdgcn_global_load_lds( \
    (const __attribute__((address_space(1))) u32*)(P[h][l] + (kt)), \
    (__attribute__((address_space(3))) u32*)(smem + (buf)*65536 + (isB)*32768 + (h)*16384 + (l)*8192 + wid*1024), \
    16, 0, 0)

#define LDB(buf) do { \
  _Pragma("unroll") for (int nf = 0; nf < 4; nf++) \
  _Pragma("unroll") for (int kk = 0; kk < 2; kk++) { \
    int rel = (wn*64 + nf*16 + lm)*128 + kk*64 + lg*16; \
    bq[nf][kk] = *(const s16x8*)(smem + (buf)*65536 + 32768 + (rel ^ (((rel>>9)&1)<<5))); \
  } } while(0)

#define LDA(buf, q) do { \
  _Pragma("unroll") for (int ml = 0; ml < 2; ml++) \
  _Pragma("unroll") for (int kk = 0; kk < 2; kk++) { \
    int rel = (wm*128 + ((q)*2+ml)*16 + lm)*128 + kk*64 + lg*16; \
    aq[ml][kk] = *(const s16x8*)(smem + (buf)*65536 + (rel ^ (((rel>>9)&1)<<5))); \
  } } while(0)

#define MFMAQ(q) do { \
  __builtin_amdgcn_s_setprio(1); \
  _Pragma("unroll") for (int ml = 0; ml < 2; ml++) \
  _Pragma("unroll") for (int nf = 0; nf < 4; nf++) \
  _Pragma("unroll") for (int kk = 0; kk < 2; kk++) \
    acc[(q)*2+ml][nf] = __builtin_amdgcn_mfma_f32_16x16x32_bf16(aq[ml][kk], bq[nf][kk], acc[(q)*2+ml][nf], 0, 0, 0); \
  __builtin_amdgcn_s_setprio(0); \
} while(0)

template<int EPI>
__global__ __launch_bounds__(512, 2)
void k_gemm256(const u16* __restrict__ A, const u16* __restrict__ W,
               const float* __restrict__ bias, u16* __restrict__ C,
               int M, int N, int K) {
  extern __shared__ char smem[];
  const int tid = threadIdx.x;
  const int lane = tid & 63;
  const int wid = tid >> 6;
  const int lm = lane & 15, lg = lane >> 4;
  const int wm = wid >> 2, wn = wid & 3;

  const int NB = N >> 8;
  const int nwg = gridDim.x;
  const int bid = blockIdx.x;
  const int cpx = nwg >> 3;
  const int swzb = (bid & 7) * cpx + (bid >> 3);
  const int m0 = (swzb / NB) << 8;
  const int n0 = (swzb % NB) << 8;

  const u16* pA[2][2];
  const u16* pB[2][2];
#pragma unroll
  for (int h = 0; h < 2; h++)
#pragma unroll
    for (int l = 0; l < 2; l++) {
      int rel = h * 16384 + l * 8192 + tid * 16;
      int sb = rel ^ (((rel >> 9) & 1) << 5);
      int grow = sb >> 7;
      int gcol = (sb & 127) >> 1;
      pA[h][l] = A + (size_t)(m0 + grow) * K + gcol;
      pB[h][l] = W + (size_t)(n0 + grow) * K + gcol;
    }

  f32x4 acc[8][4];
#pragma unroll
  for (int i = 0; i < 8; i++)
#pragma unroll
    for (int j = 0; j < 4; j++) acc[i][j] = (f32x4){0.f, 0.f, 0.f, 0.f};

  s16x8 bq[4][2];
  s16x8 aq[2][2];

  const int NT = K >> 6;

  STG(pB,1,0,0,0,0); STG(pB,1,0,1,0,0); STG(pB,1,1,0,0,0); STG(pB,1,1,1,0,0);
  STG(pA,0,0,0,0,0); STG(pA,0,0,1,0,0); STG(pA,0,1,0,0,0); STG(pA,0,1,1,0,0);
  STG(pB,1,0,0,1,64); STG(pB,1,0,1,1,64); STG(pB,1,1,0,1,64); STG(pB,1,1,1,1,64);
  VMW4;
  GBAR;

  for (int i = 0; i < (NT >> 1); i++) {
    const int t1k = (2*i + 1) * 64;
    int t2 = 2*i + 2; if (t2 >= NT) t2 -= NT;
    int t3 = 2*i + 3; if (t3 >= NT) t3 -= NT;
    const int t2k = t2 * 64, t3k = t3 * 64;

    LDB(0); LDA(0,0);
    STG(pA,0,0,0,1,t1k); STG(pA,0,0,1,1,t1k);
    GBAR; MFMAQ(0); GBAR;
    LDA(0,1);
    STG(pA,0,1,0,1,t1k); STG(pA,0,1,1,1,t1k);
    STG(pB,1,0,0,0,t2k); STG(pB,1,0,1,0,t2k);
    GBAR; MFMAQ(1); GBAR;
    LDA(0,2);
    STG(pB,1,1,0,0,t2k); STG(pB,1,1,1,0,t2k);
    GBAR; MFMAQ(2); GBAR;
    LDA(0,3);
    GBAR; MFMAQ(3); VMW4; GBAR;
    LDB(1); LDA(1,0);
    STG(pA,0,0,0,0,t2k); STG(pA,0,0,1,0,t2k);
    GBAR; MFMAQ(0); GBAR;
    LDA(1,1);
    STG(pA,0,1,0,0,t2k); STG(pA,0,1,1,0,t2k);
    GBAR; MFMAQ(1); GBAR;
    LDA(1,2);
    STG(pB,1,0,0,1,t3k); STG(pB,1,0,1,1,t3k);
    GBAR; MFMAQ(2); GBAR;
    LDA(1,3);
    STG(pB,1,1,0,1,t3k); STG(pB,1,1,1,1,t3k);
    GBAR; MFMAQ(3); VMW4; GBAR;
  }

  float bn[4];
#pragma unroll
  for (int nf = 0; nf < 4; nf++) bn[nf] = bias[n0 + wn*64 + nf*16 + lm];
#pragma unroll
  for (int mf = 0; mf < 8; mf++)
#pragma unroll
    for (int nf = 0; nf < 4; nf++) {
      int col = n0 + wn*64 + nf*16 + lm;
#pragma unroll
      for (int r = 0; r < 4; r++) {
        int row = m0 + wm*128 + mf*16 + lg*4 + r;
        float v = acc[mf][nf][r] + bn[nf];
        if (EPI == 1) v = fmaxf(v, 0.f);
        C[(size_t)row * N + col] = f2bf(v);
      }
    }
}

// ---------------- fused GRU + layer-0 QKV GEMM -----------------------------
// Blocks 0..63 run the GRU (dispatched first -> start immediately); blocks
// 64..64+nG-1 run the QKV GEMM on waves 0-7 (waves 8-9 idle through the
// barrier skeleton). Hides the 190us GRU (64 CUs) under the GEMM (192 CUs).
__global__ __launch_bounds__(640, 1)
void k_qkv_gru(const u16* __restrict__ A, const u16* __restrict__ W,
               const float* __restrict__ bias, u16* __restrict__ C,
               int M, int N, int K, int nG,
               const float* __restrict__ em, const float* __restrict__ Wih,
               const float* __restrict__ bih, const float* __restrict__ Whh,
               const float* __restrict__ bhh, float* __restrict__ emo) {
  extern __shared__ char smem[];
  if ((int)blockIdx.x < BB) {
    gru_body(em, Wih, bih, Whh, bhh, emo, blockIdx.x);
    return;
  }
  const int bid = blockIdx.x - BB;      // 0..nG-1
  const int tid = threadIdx.x;
  const int lane = tid & 63;
  const bool gact = (tid >> 6) < 8;     // waves 8-9: barrier skeleton only
  const int wid = (tid >> 6) & 7;       // clamped for address safety
  const int lm = lane & 15, lg = lane >> 4;
  const int wm = wid >> 2, wn = wid & 3;

  const int NB = N >> 8;
  const int cpx = nG >> 3;              // nG % 8 == 0
  const int swzb = (bid & 7) * cpx + (bid >> 3);
  const int m0 = (swzb / NB) << 8;
  const int n0 = (swzb % NB) << 8;

  const u16* pA[2][2];
  const u16* pB[2][2];
#pragma unroll
  for (int h = 0; h < 2; h++)
#pragma unroll
    for (int l = 0; l < 2; l++) {
      int rel = h * 16384 + l * 8192 + (tid & 511) * 16;
      int sb = rel ^ (((rel >> 9) & 1) << 5);
      int grow = sb >> 7;
      int gcol = (sb & 127) >> 1;
      pA[h][l] = A + (size_t)(m0 + grow) * K + gcol;
      pB[h][l] = W + (size_t)(n0 + grow) * K + gcol;
    }

  f32x4 acc[8][4];
#pragma unroll
  for (int i = 0; i < 8; i++)
#pragma unroll
    for (int j = 0; j < 4; j++) acc[i][j] = (f32x4){0.f, 0.f, 0.f, 0.f};

  s16x8 bq[4][2];
  s16x8 aq[2][2];

  const int NT = K >> 6;

  if (gact) {
    STG(pB,1,0,0,0,0); STG(pB,1,0,1,0,0); STG(pB,1,1,0,0,0); STG(pB,1,1,1,0,0);
    STG(pA,0,0,0,0,0); STG(pA,0,0,1,0,0); STG(pA,0,1,0,0,0); STG(pA,0,1,1,0,0);
    STG(pB,1,0,0,1,64); STG(pB,1,0,1,1,64); STG(pB,1,1,0,1,64); STG(pB,1,1,1,1,64);
  }
  VMW4;
  GBAR;

  for (int i = 0; i < (NT >> 1); i++) {
    const int t1k = (2*i + 1) * 64;
    int t2 = 2*i + 2; if (t2 >= NT) t2 -= NT;
    int t3 = 2*i + 3; if (t3 >= NT) t3 -= NT;
    const int t2k = t2 * 64, t3k = t3 * 64;

    if (gact) {
      LDB(0); LDA(0,0);
      STG(pA,0,0,0,1,t1k); STG(pA,0,0,1,1,t1k);
    }
    GBAR; if (gact) { MFMAQ(0); } GBAR;
    if (gact) {
      LDA(0,1);
      STG(pA,0,1,0,1,t1k); STG(pA,0,1,1,1,t1k);
      STG(pB,1,0,0,0,t2k); STG(pB,1,0,1,0,t2k);
    }
    GBAR; if (gact) { MFMAQ(1); } GBAR;
    if (gact) {
      LDA(0,2);
      STG(pB,1,1,0,0,t2k); STG(pB,1,1,1,0,t2k);
    }
    GBAR; if (gact) { MFMAQ(2); } GBAR;
    if (gact) { LDA(0,3); }
    GBAR; if (gact) { MFMAQ(3); } VMW4; GBAR;
    if (gact) {
      LDB(1); LDA(1,0);
      STG(pA,0,0,0,0,t2k); STG(pA,0,0,1,0,t2k);
    }
    GBAR; if (gact) { MFMAQ(0); } GBAR;
    if (gact) {
      LDA(1,1);
      STG(pA,0,1,0,0,t2k); STG(pA,0,1,1,0,t2k);
    }
    GBAR; if (gact) { MFMAQ(1); } GBAR;
    if (gact) {
      LDA(1,2);
      STG(pB,1,0,0,1,t3k); STG(pB,1,0,1,1,t3k);
    }
    GBAR; if (gact) { MFMAQ(2); } GBAR;
    if (gact) {
      LDA(1,3);
      STG(pB,1,1,0,1,t3k); STG(pB,1,1,1,1,t3k);
    }
    GBAR; if (gact) { MFMAQ(3); } VMW4; GBAR;
  }

  if (gact) {
    float bn[4];
#pragma unroll
    for (int nf = 0; nf < 4; nf++) bn[nf] = bias[n0 + wn*64 + nf*16 + lm];
#pragma unroll
    for (int mf = 0; mf < 8; mf++)
#pragma unroll
      for (int nf = 0; nf < 4; nf++) {
        int col = n0 + wn*64 + nf*16 + lm;
#pragma unroll
        for (int r = 0; r < 4; r++) {
          int row = m0 + wm*128 + mf*16 + lg*4 + r;
          float v = acc[mf][nf][r] + bn[nf];
          C[(size_t)row * N + col] = f2bf(v);
        }
      }
  }
}

// ---------------- fused causal attention (R10/R12-proven version) ----------
__global__ __launch_bounds__(256, 2)
void k_attn(const u16* __restrict__ qkv, u16* __restrict__ o) {
  const int h = blockIdx.x;     // 0..15
  const int b = blockIdx.y;     // 0..63
  const int lane = threadIdx.x & 63;
  const int w = threadIdx.x >> 6;    // q-block 0..3 (64 rows each)
  const int lm = lane & 15, lg = lane >> 4;

  __shared__ u16 Ks[64 * 64];       // [k_local][dh]
  __shared__ u16 Vt[64 * 64];       // [dh][k_local]
  __shared__ u16 Ps[4][64 * 64];    // per-wave P [q_local][k_local]

  const size_t tokbase = (size_t)b * SS;

  s16x8 aq[4][2];
#pragma unroll
  for (int mf = 0; mf < 4; mf++) {
    const u16* qrow = qkv + (tokbase + w * 64 + mf * 16 + lm) * 3072 + h * 64;
#pragma unroll
    for (int kk = 0; kk < 2; kk++)
      aq[mf][kk] = *(const s16x8*)(qrow + kk * 32 + lg * 8);
  }

  f32x4 zero = {0.f, 0.f, 0.f, 0.f};
  f32x4 oacc[4][4];
#pragma unroll
  for (int mf = 0; mf < 4; mf++)
#pragma unroll
    for (int df = 0; df < 4; df++) oacc[mf][df] = zero;
  float m_run[16], l_run[16];
#pragma unroll
  for (int r = 0; r < 16; r++) { m_run[r] = -3e38f; l_run[r] = 0.f; }

  for (int kb = 0; kb < 4; kb++) {
    __syncthreads();
    {
      int krow = threadIdx.x >> 2;
      int seg  = (threadIdx.x & 3) * 16;
      const u16* ksrc = qkv + (tokbase + kb * 64 + krow) * 3072 + 1024 + h * 64 + seg;
      s16x8 v0 = *(const s16x8*)(ksrc);
      s16x8 v1 = *(const s16x8*)(ksrc + 8);
      *(s16x8*)&Ks[krow * 64 + seg] = v0;
      *(s16x8*)&Ks[krow * 64 + seg + 8] = v1;
      const u16* vsrc = qkv + (tokbase + kb * 64 + krow) * 3072 + 2048 + h * 64 + seg;
      s16x8 w0 = *(const s16x8*)(vsrc);
      s16x8 w1 = *(const s16x8*)(vsrc + 8);
#pragma unroll
      for (int e = 0; e < 8; e++) {
        Vt[(seg + e) * 64 + krow]     = (u16)w0[e];
        Vt[(seg + 8 + e) * 64 + krow] = (u16)w1[e];
      }
    }
    __syncthreads();
    if (w < kb) continue;

    s16x8 bk[4][2];
#pragma unroll
    for (int nf = 0; nf < 4; nf++)
#pragma unroll
      for (int kk = 0; kk < 2; kk++)
        bk[nf][kk] = *(const s16x8*)&Ks[(nf * 16 + lm) * 64 + kk * 32 + lg * 8];

    const int colbase = kb * 64;
#pragma unroll
    for (int mf = 0; mf < 4; mf++) {
      f32x4 sfr[4];
#pragma unroll
      for (int nf = 0; nf < 4; nf++) {
        f32x4 acc = zero;
#pragma unroll
        for (int kk = 0; kk < 2; kk++)
          acc = __builtin_amdgcn_mfma_f32_16x16x32_bf16(aq[mf][kk], bk[nf][kk], acc, 0, 0, 0);
        sfr[nf] = acc;
      }
      const int rowbase = w * 64 + mf * 16 + lg * 4;
#pragma unroll
      for (int nf = 0; nf < 4; nf++) {
        int col = colbase + nf * 16 + lm;
#pragma unroll
        for (int r = 0; r < 4; r++) {
          float v = sfr[nf][r] * 0.125f;
          sfr[nf][r] = (col <= rowbase + r) ? v : -1e30f;
        }
      }
#pragma unroll
      for (int r = 0; r < 4; r++) {
        float m = fmaxf(fmaxf(sfr[0][r], sfr[1][r]), fmaxf(sfr[2][r], sfr[3][r]));
#pragma unroll
        for (int off = 1; off < 16; off <<= 1) m = fmaxf(m, __shfl_xor(m, off));
        int idx = mf * 4 + r;
        float mnew = fmaxf(m_run[idx], m);
        float fo = __expf(m_run[idx] - mnew);
        m_run[idx] = mnew;
        float ps = 0.f;
#pragma unroll
        for (int nf = 0; nf < 4; nf++) {
          float p = __expf(sfr[nf][r] - mnew);
          sfr[nf][r] = p;
          ps += p;
        }
#pragma unroll
        for (int off = 1; off < 16; off <<= 1) ps += __shfl_xor(ps, off);
        l_run[idx] = l_run[idx] * fo + ps;
#pragma unroll
        for (int df = 0; df < 4; df++) oacc[mf][df][r] *= fo;
      }
#pragma unroll
      for (int nf = 0; nf < 4; nf++)
#pragma unroll
        for (int r = 0; r < 4; r++)
          Ps[w][(mf * 16 + lg * 4 + r) * 64 + nf * 16 + lm] = f2bf(sfr[nf][r]);
    }
    asm volatile("" ::: "memory");
    s16x8 bv[4][2];
#pragma unroll
    for (int df = 0; df < 4; df++)
#pragma unroll
      for (int kk = 0; kk < 2; kk++)
        bv[df][kk] = *(const s16x8*)&Vt[(df * 16 + lm) * 64 + kk * 32 + lg * 8];
#pragma unroll
    for (int mf = 0; mf < 4; mf++) {
      s16x8 pa[2];
#pragma unroll
      for (int kk = 0; kk < 2; kk++)
        pa[kk] = *(const s16x8*)&Ps[w][(mf * 16 + lm) * 64 + kk * 32 + lg * 8];
#pragma unroll
      for (int df = 0; df < 4; df++)
#pragma unroll
        for (int kk = 0; kk < 2; kk++)
          oacc[mf][df] = __builtin_amdgcn_mfma_f32_16x16x32_bf16(pa[kk], bv[df][kk], oacc[mf][df], 0, 0, 0);
    }
  }

#pragma unroll
  for (int mf = 0; mf < 4; mf++)
#pragma unroll
    for (int df = 0; df < 4; df++)
#pragma unroll
      for (int r = 0; r < 4; r++) {
        int row = w * 64 + mf * 16 + lg * 4 + r;
        float val = oacc[mf][df][r] / l_run[mf * 4 + r];
        o[(tokbase + row) * 1024 + h * 64 + df * 16 + lm] = f2bf(val);
      }
}

// ---------------- residual + LayerNorm: wave-per-row, shfl-only ------------
__global__ __launch_bounds__(256)
void k_ln(u16* __restrict__ xb, const u16* __restrict__ tmp,
          const float* __restrict__ gam, const float* __restrict__ bet) {
  int t = blockIdx.x * 4 + (threadIdx.x >> 6);
  int lane = threadIdx.x & 63;
  size_t base = (size_t)t * DD + lane * 16;
  u16x8 a0 = *(const u16x8*)(xb + base);
  u16x8 a1 = *(const u16x8*)(xb + base + 8);
  u16x8 u0 = *(const u16x8*)(tmp + base);
  u16x8 u1 = *(const u16x8*)(tmp + base + 8);
  f32x4 v0, v1, v2, v3;
#pragma unroll
  for (int e = 0; e < 4; e++) {
    v0[e] = bf2f(a0[e]) + bf2f(u0[e]);
    v1[e] = bf2f(a0[4 + e]) + bf2f(u0[4 + e]);
    v2[e] = bf2f(a1[e]) + bf2f(u1[e]);
    v3[e] = bf2f(a1[4 + e]) + bf2f(u1[4 + e]);
  }
  float s = 0.f, s2 = 0.f;
#pragma unroll
  for (int e = 0; e < 4; e++) {
    s  += v0[e] + v1[e] + v2[e] + v3[e];
    s2 += v0[e]*v0[e] + v1[e]*v1[e] + v2[e]*v2[e] + v3[e]*v3[e];
  }
#pragma unroll
  for (int off = 32; off >= 1; off >>= 1) {
    s  += __shfl_xor(s, off);
    s2 += __shfl_xor(s2, off);
  }
  float mean = s * (1.f / 1024.f);
  float var = s2 * (1.f / 1024.f) - mean * mean;
  float rstd = rsqrtf(var + 1e-5f);
  const float* gp = gam + lane * 16;
  const float* bp = bet + lane * 16;
  f32x4 g0 = *(const f32x4*)(gp), g1 = *(const f32x4*)(gp + 4);
  f32x4 g2 = *(const f32x4*)(gp + 8), g3 = *(const f32x4*)(gp + 12);
  f32x4 b0 = *(const f32x4*)(bp), b1 = *(const f32x4*)(bp + 4);
  f32x4 b2 = *(const f32x4*)(bp + 8), b3 = *(const f32x4*)(bp + 12);
  u16x8 y0, y1;
#pragma unroll
  for (int e = 0; e < 4; e++) {
    y0[e]     = f2bf((v0[e] - mean) * rstd * g0[e] + b0[e]);
    y0[4 + e] = f2bf((v1[e] - mean) * rstd * g1[e] + b1[e]);
    y1[e]     = f2bf((v2[e] - mean) * rstd * g2[e] + b2[e]);
    y1[4 + e] = f2bf((v3[e] - mean) * rstd * g3[e] + b3[e]);
  }
  *(u16x8*)(xb + base) = y0;
  *(u16x8*)(xb + base + 8) = y1;
}

// ---------------- main-token dot precompute (x is bf16) ----------------
__global__ void k_main(const int* __restrict__ d_ids, const int* __restrict__ ut_len,
                       const u16* __restrict__ x, const float* __restrict__ decW,
                       float* __restrict__ md) {
  int b = blockIdx.x;
  int lane = threadIdx.x;   // 64
  int len = ut_len[d_ids[b]];
  const u16* xr = x + ((size_t)b * SS + (len - 1)) * DD;
  float acc[NCC];
#pragma unroll
  for (int c = 0; c < NCC; c++) acc[c] = 0.f;
  for (int d = lane; d < DD; d += 64) {
    float xv = bf2f(xr[d]);
#pragma unroll
    for (int c = 0; c < NCC; c++) acc[c] += xv * decW[(size_t)c * 2148 + 1024 + d];
  }
#pragma unroll
  for (int c = 0; c < NCC; c++) {
#pragma unroll
    for (int off = 32; off >= 1; off >>= 1) acc[c] += __shfl_xor(acc[c], off);
  }
  if (lane == 0) {
#pragma unroll
    for (int c = 0; c < NCC; c++) md[b * NCC + c] = acc[c];
  }
}

// ---------------- decoder (x is bf16) ----------------
__global__ __launch_bounds__(256)
void k_dec(const u16* __restrict__ x, const float* __restrict__ emo,
           const float* __restrict__ md, const float* __restrict__ decW,
           const float* __restrict__ decb, const int* __restrict__ d_ids,
           const int* __restrict__ ut_len, float* __restrict__ out) {
  int grp = threadIdx.x >> 6, lane = threadIdx.x & 63;
  int t = blockIdx.x * 4 + grp;
  int b = t / SS, s = t % SS;
  int len = ut_len[d_ids[b]];
  bool valid = s < len;
  float acc[NCC];
#pragma unroll
  for (int c = 0; c < NCC; c++) acc[c] = 0.f;
  if (valid) {
    const u16* xrow = x + (size_t)t * DD;
    for (int d = lane; d < DD; d += 64) {
      float xv = bf2f(xrow[d]);
#pragma unroll
      for (int c = 0; c < NCC; c++) acc[c] += xv * decW[(size_t)c * 2148 + d];
    }
  }
  {
    const float* er = emo + (size_t)t * GHH;
    for (int d = lane; d < GHH; d += 64) {
      float ev = er[d];
#pragma unroll
      for (int c = 0; c < NCC; c++) acc[c] += ev * decW[(size_t)c * 2148 + 2048 + d];
    }
  }
#pragma unroll
  for (int c = 0; c < NCC; c++) {
#pragma unroll
    for (int off = 32; off >= 1; off >>= 1) acc[c] += __shfl_xor(acc[c], off);
  }
  if (lane == 0) {
#pragma unroll
    for (int c = 0; c < NCC; c++) {
      float v = acc[c] + (valid ? md[b * NCC + c] : 0.f) + decb[c];
      out[(size_t)t * NCC + c] = v;
    }
  }
}

// ---------------- launch ----------------
extern "C" void kernel_launch(void* const* d_in, const int* in_sizes, int n_in,
                              void* d_out, int out_size, void* d_ws, size_t ws_size,
                              hipStream_t stream) {
  const int*   src    = (const int*)d_in[0];
  const float* em_seq = (const float*)d_in[1];
  const int*   d_ids  = (const int*)d_in[2];
  const int*   ut_len = (const int*)d_in[3];
  const float* emb    = (const float*)d_in[4];
  const float* Wqkv   = (const float*)d_in[5];
  const float* bqkv   = (const float*)d_in[6];
  const float* Wo     = (const float*)d_in[7];
  const float* bo     = (const float*)d_in[8];
  const float* W1     = (const float*)d_in[9];
  const float* b1     = (const float*)d_in[10];
  const float* W2     = (const float*)d_in[11];
  const float* b2     = (const float*)d_in[12];
  const float* ln1g   = (const float*)d_in[13];
  const float* ln1b   = (const float*)d_in[14];
  const float* ln2g   = (const float*)d_in[15];
  const float* ln2b   = (const float*)d_in[16];
  const float* gWih   = (const float*)d_in[17];
  const float* gWhh   = (const float*)d_in[18];
  const float* gbih   = (const float*)d_in[19];
  const float* gbhh   = (const float*)d_in[20];
  const float* decW   = (const float*)d_in[21];
  const float* decb   = (const float*)d_in[22];
  float* out = (float*)d_out;

  char* wsp = (char*)d_ws;
  auto take = [&](size_t n) { char* p = wsp; wsp += (n + 255) & ~(size_t)255; return p; };

  u16*   wqkvb = (u16*)take((size_t)3072 * 1024 * 2);
  u16*   wob   = (u16*)take((size_t)1024 * 1024 * 2);
  u16*   w1b   = (u16*)take((size_t)4096 * 1024 * 2);
  u16*   w2b   = (u16*)take((size_t)1024 * 4096 * 2);
  float* pe    = (float*)take((size_t)SS * DD * 4);
  u16*   xb    = (u16*)take((size_t)TT * DD * 2);
  u16*   big   = (u16*)take((size_t)TT * FFN * 2);
  u16*   ob    = (u16*)take((size_t)TT * DD * 2);
  u16*   tmp16 = (u16*)take((size_t)TT * DD * 2);
  float* emo   = (float*)take((size_t)BB * SS * GHH * 4);
  float* md    = (float*)take((size_t)BB * NCC * 4);

  (void)hipFuncSetAttribute((const void*)&k_gemm256<0>,
      hipFuncAttributeMaxDynamicSharedMemorySize, 131072);
  (void)hipFuncSetAttribute((const void*)&k_gemm256<1>,
      hipFuncAttributeMaxDynamicSharedMemorySize, 131072);
  (void)hipFuncSetAttribute((const void*)&k_qkv_gru,
      hipFuncAttributeMaxDynamicSharedMemorySize, 131072);

  // embedding + positional encoding
  k_pe<<<(SS * DD / 2 + 255) / 256, 256, 0, stream>>>(pe);
  k_embed<<<TT * DD / 4 / 256, 256, 0, stream>>>(src, emb, pe, xb);

  const int nG_qkv = (TT / 256) * (3072 / 256);   // 768

  for (int l = 0; l < LL; ++l) {
    k_f2bf4<<<2048, 256, 0, stream>>>(
        Wqkv + (size_t)l * 3072 * 1024, wqkvb, 3072 * 1024 / 4,
        Wo   + (size_t)l * 1024 * 1024, wob,   1024 * 1024 / 4,
        W1   + (size_t)l * 4096 * 1024, w1b,   4096 * 1024 / 4,
        W2   + (size_t)l * 1024 * 4096, w2b,   1024 * 4096 / 4);

    if (l == 0) {
      // fused: GRU (blocks 0-63) + QKV layer-0 (blocks 64..)
      k_qkv_gru<<<BB + nG_qkv, 640, 131072, stream>>>(
          xb, wqkvb, bqkv, big, TT, 3072, 1024, nG_qkv,
          em_seq, gWih, gbih, gWhh, gbhh, emo);
    } else {
      k_gemm256<0><<<nG_qkv, 512, 131072, stream>>>(
          xb, wqkvb, bqkv + (size_t)l * 3072, big, TT, 3072, 1024);
    }
    // attention
    k_attn<<<dim3(HH, BB), 256, 0, stream>>>(big, ob);
    // output projection
    k_gemm256<0><<<(TT/256) * (1024/256), 512, 131072, stream>>>(
        ob, wob, bo + (size_t)l * 1024, tmp16, TT, 1024, 1024);
    // residual + LN1  (xb <- LN(xb + tmp16))
    k_ln<<<TT / 4, 256, 0, stream>>>(xb, tmp16, ln1g + (size_t)l * DD, ln1b + (size_t)l * DD);
    // FFN1 (relu)
    k_gemm256<1><<<(TT/256) * (4096/256), 512, 131072, stream>>>(
        xb, w1b, b1 + (size_t)l * 4096, big, TT, 4096, 1024);
    // FFN2
    k_gemm256<0><<<(TT/256) * (1024/256), 512, 131072, stream>>>(
        big, w2b, b2 + (size_t)l * 1024, tmp16, TT, 1024, 4096);
    // residual + LN2  (xb <- LN(xb + tmp16))
    k_ln<<<TT / 4, 256, 0, stream>>>(xb, tmp16, ln2g + (size_t)l * DD, ln2b + (size_t)l * DD);
  }

  // decoder
  k_main<<<BB, 64, 0, stream>>>(d_ids, ut_len, xb, decW, md);
  k_dec<<<TT / 4, 256, 0, stream>>>(xb, emo, md, decW, decb, d_ids, ut_len, out);
}

// Round 16
// 2253.252 us; speedup vs baseline: 1.1731x; 1.1731x over previous
//
#include <hip/hip_runtime.h>
#include <hip/hip_bf16.h>
#include <math.h>

// Problem constants
#define BB 64
#define SS 256
#define DD 1024
#define HH 16
#define FFN 4096
#define GHH 100
#define NCC 7
#define LL 4
#define TT (BB*SS)          // 16384 tokens
#define DHH 64

typedef unsigned short u16;
typedef unsigned int u32;
typedef __attribute__((ext_vector_type(4))) float f32x4;
typedef __attribute__((ext_vector_type(8))) short s16x8;
typedef __attribute__((ext_vector_type(4))) unsigned short u16x4;
typedef __attribute__((ext_vector_type(8))) unsigned short u16x8;

__device__ __forceinline__ u16 f2bf(float f) {
  union { float f; u32 u; } x; x.f = f;
  u32 r = x.u + 0x7FFFu + ((x.u >> 16) & 1u);
  return (u16)(r >> 16);
}
__device__ __forceinline__ float bf2f(u16 b) {
  union { u32 u; float f; } x; x.u = ((u32)b) << 16;
  return x.f;
}
__device__ __forceinline__ u32 pkbf(float a, float b) {
  return (u32)f2bf(a) | ((u32)f2bf(b) << 16);
}
__device__ __forceinline__ float lo16(u32 u) {
  union { u32 u; float f; } x; x.u = u << 16; return x.f;
}
__device__ __forceinline__ float hi16(u32 u) {
  union { u32 u; float f; } x; x.u = u & 0xffff0000u; return x.f;
}

// per-layer bf16 weight layout inside the big workspace block (f32x4 units)
#define LS4   3145728          // 12582912 elems / 4
#define QKV4  786432
#define WO4   262144
#define W14   1048576

// ---------------- positional encoding ----------------
__global__ void k_pe(float* __restrict__ pe) {
  int i = blockIdx.x * blockDim.x + threadIdx.x;     // over S*D/2
  if (i >= SS * DD / 2) return;
  int s = i / (DD / 2), j = i % (DD / 2);
  float div = __expf((float)(2 * j) * (-9.210340371976184f / (float)DD));
  float a = (float)s * div;
  pe[s * DD + 2 * j]     = sinf(a);
  pe[s * DD + 2 * j + 1] = cosf(a);
}

// ---------------- embedding + PE (single bf16 stream) ----------------
__global__ void k_embed(const int* __restrict__ src, const float* __restrict__ emb,
                        const float* __restrict__ pe, u16* __restrict__ xb) {
  int i = blockIdx.x * blockDim.x + threadIdx.x;     // over T*D/4
  if (i >= TT * DD / 4) return;
  int t = i / (DD / 4);
  int d4 = (i % (DD / 4)) * 4;
  int s = t % SS;
  int tok = src[t];
  f32x4 e = *(const f32x4*)(emb + (size_t)tok * DD + d4);
  f32x4 p = *(const f32x4*)(pe + (size_t)s * DD + d4);
  u16x4 o;
  o[0] = f2bf(e[0] * 32.0f + p[0]); o[1] = f2bf(e[1] * 32.0f + p[1]);
  o[2] = f2bf(e[2] * 32.0f + p[2]); o[3] = f2bf(e[3] * 32.0f + p[3]);
  *(u16x4*)(xb + (size_t)t * DD + d4) = o;
}

// ---------------- GRU body (R10-proven; device fn for fusion) --------------
#define F7(X) X(0) X(1) X(2) X(3) X(4) X(5) X(6)
#define C12(X) X(0) X(1) X(2) X(3) X(4) X(5) X(6) X(7) X(8) X(9) X(10) X(11)

__device__ __forceinline__
void gru_body(const float* __restrict__ em, const float* __restrict__ Wih,
              const float* __restrict__ bih, const float* __restrict__ Whh,
              const float* __restrict__ bhh, float* __restrict__ emo, int b) {
  const int tid = threadIdx.x;
  const int iraw = tid / 6;
  const int sub = tid - iraw * 6;
  const int g = sub >> 1, half = sub & 1;
  const bool act = iraw < 100;
  const int i = act ? iraw : 99;
  const int grow = g * 100 + i;

  __shared__ __align__(16) float h[2][104];
  __shared__ float vals[400];
  __shared__ __align__(16) float emL[SS][8];
  __shared__ float emoL[16][100];

  const float* rowP = Whh + (size_t)grow * 100 + half * 50;
#define LW(q) u32 wa##q = pkbf(rowP[4*(q)], rowP[4*(q)+1]); \
              u32 wb##q = pkbf(rowP[4*(q)+2], rowP[4*(q)+3]); \
              asm volatile("" : "+v"(wa##q), "+v"(wb##q));
  C12(LW)
#undef LW
  u32 wt = pkbf(rowP[48], rowP[49]);
  asm volatile("" : "+v"(wt));

#define LI(f) float wi##f = Wih[grow * 7 + (f)];
  F7(LI)
#undef LI
  const float bhhv = bhh[grow];
  const float bihv = bih[grow];

  {
    const float* ebase = em + (size_t)b * SS * 7;
    for (int idx = tid; idx < SS * 7; idx += 640) {
      int ss = idx / 7, ff = idx - ss * 7;
      emL[ss][ff] = ebase[idx];
    }
  }
  if (tid < 104) { h[0][tid] = 0.f; h[1][tid] = 0.f; }
  __syncthreads();

  for (int s = 0; s < SS; ++s) {
    const float* hc = h[s & 1];
    float* hb_next = h[(s & 1) ^ 1];
    float xp = bihv;
#define MI(f) xp += wi##f * emL[s][f];
    F7(MI)
#undef MI
    const float* hbp = hc + half * 52;
    float a0 = 0.f, a1 = 0.f, a2 = 0.f, a3 = 0.f;
#define MC(q) { f32x4 hv = *(const f32x4*)(hbp + 4*(q)); \
    a0 += lo16(wa##q) * hv[0]; a1 += hi16(wa##q) * hv[1]; \
    a2 += lo16(wb##q) * hv[2]; a3 += hi16(wb##q) * hv[3]; }
    C12(MC)
#undef MC
    { a0 += lo16(wt) * hbp[48]; a1 += hi16(wt) * hbp[49]; }
    float a = (a0 + a1) + (a2 + a3);
    a += __shfl_xor(a, 1);
    if (act && half == 0) {
      if (g == 2) { vals[200 + i] = xp; vals[300 + i] = a + bhhv; }
      else        { vals[g * 100 + i] = xp + a + bhhv; }
    }
    __syncthreads();
    if (tid < 100) {
      int slot = tid + (tid >= 50 ? 2 : 0);
      float hold = hc[slot];
      float rr = 1.f / (1.f + __expf(-vals[tid]));
      float zz = 1.f / (1.f + __expf(-vals[100 + tid]));
      float nx = vals[200 + tid] + rr * vals[300 + tid];
      float e2 = __expf(-2.f * fabsf(nx));
      float th = (1.f - e2) / (1.f + e2);
      float nn = copysignf(th, nx);
      float hv = (1.f - zz) * nn + zz * hold;
      hb_next[slot] = hv;
      emoL[s & 15][tid] = hv;
    }
    __syncthreads();
    if ((s & 15) == 15) {
      float* dst = emo + ((size_t)b * SS + (s - 15)) * GHH;
      for (int idx = tid; idx < 16 * GHH; idx += 640)
        dst[idx] = (&emoL[0][0])[idx];
    }
  }
}

// ---------------- fused GRU + all-layer weight conversion ------------------
// Blocks 0..63: GRU (64 CUs, ~190us serial scan). Blocks 64+: grid-stride
// fp32->bf16 convert of ALL 4 layers' weights (pure HBM streaming, no LDS,
// no barriers executed) -> runs on the other CUs, hiding the GRU.
__global__ __launch_bounds__(640, 1)
void k_gru_conv(const float* __restrict__ em, const float* __restrict__ Wih,
                const float* __restrict__ bih, const float* __restrict__ Whh,
                const float* __restrict__ bhh, float* __restrict__ emo,
                const float* __restrict__ Wqkv, const float* __restrict__ Wo,
                const float* __restrict__ W1, const float* __restrict__ W2,
                u16* __restrict__ wall) {
  if ((int)blockIdx.x < BB) {
    gru_body(em, Wih, bih, Whh, bhh, emo, blockIdx.x);
    return;
  }
  const int idx0 = ((int)blockIdx.x - BB) * 640 + threadIdx.x;
  const int stride = ((int)gridDim.x - BB) * 640;
  const int nTot4 = LL * LS4;                  // 12582912 f32x4 groups
  for (int i = idx0; i < nTot4; i += stride) {
    int l = i / LS4;
    int r = i - l * LS4;                        // f32x4 units within layer
    const float* s;
    if (r < QKV4)                 s = Wqkv + ((size_t)l * QKV4 + r) * 4;
    else if (r < QKV4 + WO4)      s = Wo   + ((size_t)l * WO4  + (r - QKV4)) * 4;
    else if (r < QKV4 + WO4 + W14) s = W1  + ((size_t)l * W14  + (r - QKV4 - WO4)) * 4;
    else                          s = W2   + ((size_t)l * W14  + (r - QKV4 - WO4 - W14)) * 4;
    f32x4 v = *(const f32x4*)s;
    u16x4 o;
    o[0] = f2bf(v[0]); o[1] = f2bf(v[1]); o[2] = f2bf(v[2]); o[3] = f2bf(v[3]);
    *(u16x4*)(wall + (size_t)i * 4) = o;
  }
}

// ---------------- 256x256 8-phase GEMM (T1+T2+T3+T4+T5) ----------------
#define MEMF asm volatile("" ::: "memory")
#define GBAR do { MEMF; __builtin_amdgcn_sched_barrier(0); __builtin_amdgcn_s_barrier(); __builtin_amdgcn_sched_barrier(0); MEMF; } while(0)
#define VMW4 asm volatile("s_waitcnt vmcnt(4)" ::: "memory")

#define STG(P, isB, h, l, buf, kt) \
  __builtin_amdgcn_global_load_lds( \
    (const __attribute__((address_space(1))) u32*)(P[h][l] + (kt)), \
    (__attribute__((address_space(3))) u32*)(smem + (buf)*65536 + (isB)*32768 + (h)*16384 + (l)*8192 + wid*1024), \
    16, 0, 0)

#define LDB(buf) do { \
  _Pragma("unroll") for (int nf = 0; nf < 4; nf++) \
  _Pragma("unroll") for (int kk = 0; kk < 2; kk++) { \
    int rel = (wn*64 + nf*16 + lm)*128 + kk*64 + lg*16; \
    bq[nf][kk] = *(const s16x8*)(smem + (buf)*65536 + 32768 + (rel ^ (((rel>>9)&1)<<5))); \
  } } while(0)

#define LDA(buf, q) do { \
  _Pragma("unroll") for (int ml = 0; ml < 2; ml++) \
  _Pragma("unroll") for (int kk = 0; kk < 2; kk++) { \
    int rel = (wm*128 + ((q)*2+ml)*16 + lm)*128 + kk*64 + lg*16; \
    aq[ml][kk] = *(const s16x8*)(smem + (buf)*65536 + (rel ^ (((rel>>9)&1)<<5))); \
  } } while(0)

#define MFMAQ(q) do { \
  __builtin_amdgcn_s_setprio(1); \
  _Pragma("unroll") for (int ml = 0; ml < 2; ml++) \
  _Pragma("unroll") for (int nf = 0; nf < 4; nf++) \
  _Pragma("unroll") for (int kk = 0; kk < 2; kk++) \
    acc[(q)*2+ml][nf] = __builtin_amdgcn_mfma_f32_16x16x32_bf16(aq[ml][kk], bq[nf][kk], acc[(q)*2+ml][nf], 0, 0, 0); \
  __builtin_amdgcn_s_setprio(0); \
} while(0)

template<int EPI>
__global__ __launch_bounds__(512, 2)
void k_gemm256(const u16* __restrict__ A, const u16* __restrict__ W,
               const float* __restrict__ bias, u16* __restrict__ C,
               int M, int N, int K) {
  extern __shared__ char smem[];
  const int tid = threadIdx.x;
  const int lane = tid & 63;
  const int wid = tid >> 6;
  const int lm = lane & 15, lg = lane >> 4;
  const int wm = wid >> 2, wn = wid & 3;

  const int NB = N >> 8;
  const int nwg = gridDim.x;
  const int bid = blockIdx.x;
  const int cpx = nwg >> 3;
  const int swzb = (bid & 7) * cpx + (bid >> 3);
  const int m0 = (swzb / NB) << 8;
  const int n0 = (swzb % NB) << 8;

  const u16* pA[2][2];
  const u16* pB[2][2];
#pragma unroll
  for (int h = 0; h < 2; h++)
#pragma unroll
    for (int l = 0; l < 2; l++) {
      int rel = h * 16384 + l * 8192 + tid * 16;
      int sb = rel ^ (((rel >> 9) & 1) << 5);
      int grow = sb >> 7;
      int gcol = (sb & 127) >> 1;
      pA[h][l] = A + (size_t)(m0 + grow) * K + gcol;
      pB[h][l] = W + (size_t)(n0 + grow) * K + gcol;
    }

  f32x4 acc[8][4];
#pragma unroll
  for (int i = 0; i < 8; i++)
#pragma unroll
    for (int j = 0; j < 4; j++) acc[i][j] = (f32x4){0.f, 0.f, 0.f, 0.f};

  s16x8 bq[4][2];
  s16x8 aq[2][2];

  const int NT = K >> 6;

  STG(pB,1,0,0,0,0); STG(pB,1,0,1,0,0); STG(pB,1,1,0,0,0); STG(pB,1,1,1,0,0);
  STG(pA,0,0,0,0,0); STG(pA,0,0,1,0,0); STG(pA,0,1,0,0,0); STG(pA,0,1,1,0,0);
  STG(pB,1,0,0,1,64); STG(pB,1,0,1,1,64); STG(pB,1,1,0,1,64); STG(pB,1,1,1,1,64);
  VMW4;
  GBAR;

  for (int i = 0; i < (NT >> 1); i++) {
    const int t1k = (2*i + 1) * 64;
    int t2 = 2*i + 2; if (t2 >= NT) t2 -= NT;
    int t3 = 2*i + 3; if (t3 >= NT) t3 -= NT;
    const int t2k = t2 * 64, t3k = t3 * 64;

    LDB(0); LDA(0,0);
    STG(pA,0,0,0,1,t1k); STG(pA,0,0,1,1,t1k);
    GBAR; MFMAQ(0); GBAR;
    LDA(0,1);
    STG(pA,0,1,0,1,t1k); STG(pA,0,1,1,1,t1k);
    STG(pB,1,0,0,0,t2k); STG(pB,1,0,1,0,t2k);
    GBAR; MFMAQ(1); GBAR;
    LDA(0,2);
    STG(pB,1,1,0,0,t2k); STG(pB,1,1,1,0,t2k);
    GBAR; MFMAQ(2); GBAR;
    LDA(0,3);
    GBAR; MFMAQ(3); VMW4; GBAR;
    LDB(1); LDA(1,0);
    STG(pA,0,0,0,0,t2k); STG(pA,0,0,1,0,t2k);
    GBAR; MFMAQ(0); GBAR;
    LDA(1,1);
    STG(pA,0,1,0,0,t2k); STG(pA,0,1,1,0,t2k);
    GBAR; MFMAQ(1); GBAR;
    LDA(1,2);
    STG(pB,1,0,0,1,t3k); STG(pB,1,0,1,1,t3k);
    GBAR; MFMAQ(2); GBAR;
    LDA(1,3);
    STG(pB,1,1,0,1,t3k); STG(pB,1,1,1,1,t3k);
    GBAR; MFMAQ(3); VMW4; GBAR;
  }

  float bn[4];
#pragma unroll
  for (int nf = 0; nf < 4; nf++) bn[nf] = bias[n0 + wn*64 + nf*16 + lm];
#pragma unroll
  for (int mf = 0; mf < 8; mf++)
#pragma unroll
    for (int nf = 0; nf < 4; nf++) {
      int col = n0 + wn*64 + nf*16 + lm;
#pragma unroll
      for (int r = 0; r < 4; r++) {
        int row = m0 + wm*128 + mf*16 + lg*4 + r;
        float v = acc[mf][nf][r] + bn[nf];
        if (EPI == 1) v = fmaxf(v, 0.f);
        C[(size_t)row * N + col] = f2bf(v);
      }
    }
}

// ---------------- fused causal attention (R10/R12-proven version) ----------
__global__ __launch_bounds__(256, 2)
void k_attn(const u16* __restrict__ qkv, u16* __restrict__ o) {
  const int h = blockIdx.x;     // 0..15
  const int b = blockIdx.y;     // 0..63
  const int lane = threadIdx.x & 63;
  const int w = threadIdx.x >> 6;    // q-block 0..3 (64 rows each)
  const int lm = lane & 15, lg = lane >> 4;

  __shared__ u16 Ks[64 * 64];       // [k_local][dh]
  __shared__ u16 Vt[64 * 64];       // [dh][k_local]
  __shared__ u16 Ps[4][64 * 64];    // per-wave P [q_local][k_local]

  const size_t tokbase = (size_t)b * SS;

  s16x8 aq[4][2];
#pragma unroll
  for (int mf = 0; mf < 4; mf++) {
    const u16* qrow = qkv + (tokbase + w * 64 + mf * 16 + lm) * 3072 + h * 64;
#pragma unroll
    for (int kk = 0; kk < 2; kk++)
      aq[mf][kk] = *(const s16x8*)(qrow + kk * 32 + lg * 8);
  }

  f32x4 zero = {0.f, 0.f, 0.f, 0.f};
  f32x4 oacc[4][4];
#pragma unroll
  for (int mf = 0; mf < 4; mf++)
#pragma unroll
    for (int df = 0; df < 4; df++) oacc[mf][df] = zero;
  float m_run[16], l_run[16];
#pragma unroll
  for (int r = 0; r < 16; r++) { m_run[r] = -3e38f; l_run[r] = 0.f; }

  for (int kb = 0; kb < 4; kb++) {
    __syncthreads();
    {
      int krow = threadIdx.x >> 2;
      int seg  = (threadIdx.x & 3) * 16;
      const u16* ksrc = qkv + (tokbase + kb * 64 + krow) * 3072 + 1024 + h * 64 + seg;
      s16x8 v0 = *(const s16x8*)(ksrc);
      s16x8 v1 = *(const s16x8*)(ksrc + 8);
      *(s16x8*)&Ks[krow * 64 + seg] = v0;
      *(s16x8*)&Ks[krow * 64 + seg + 8] = v1;
      const u16* vsrc = qkv + (tokbase + kb * 64 + krow) * 3072 + 2048 + h * 64 + seg;
      s16x8 w0 = *(const s16x8*)(vsrc);
      s16x8 w1 = *(const s16x8*)(vsrc + 8);
#pragma unroll
      for (int e = 0; e < 8; e++) {
        Vt[(seg + e) * 64 + krow]     = (u16)w0[e];
        Vt[(seg + 8 + e) * 64 + krow] = (u16)w1[e];
      }
    }
    __syncthreads();
    if (w < kb) continue;

    s16x8 bk[4][2];
#pragma unroll
    for (int nf = 0; nf < 4; nf++)
#pragma unroll
      for (int kk = 0; kk < 2; kk++)
        bk[nf][kk] = *(const s16x8*)&Ks[(nf * 16 + lm) * 64 + kk * 32 + lg * 8];

    const int colbase = kb * 64;
#pragma unroll
    for (int mf = 0; mf < 4; mf++) {
      f32x4 sfr[4];
#pragma unroll
      for (int nf = 0; nf < 4; nf++) {
        f32x4 acc = zero;
#pragma unroll
        for (int kk = 0; kk < 2; kk++)
          acc = __builtin_amdgcn_mfma_f32_16x16x32_bf16(aq[mf][kk], bk[nf][kk], acc, 0, 0, 0);
        sfr[nf] = acc;
      }
      const int rowbase = w * 64 + mf * 16 + lg * 4;
#pragma unroll
      for (int nf = 0; nf < 4; nf++) {
        int col = colbase + nf * 16 + lm;
#pragma unroll
        for (int r = 0; r < 4; r++) {
          float v = sfr[nf][r] * 0.125f;
          sfr[nf][r] = (col <= rowbase + r) ? v : -1e30f;
        }
      }
#pragma unroll
      for (int r = 0; r < 4; r++) {
        float m = fmaxf(fmaxf(sfr[0][r], sfr[1][r]), fmaxf(sfr[2][r], sfr[3][r]));
#pragma unroll
        for (int off = 1; off < 16; off <<= 1) m = fmaxf(m, __shfl_xor(m, off));
        int idx = mf * 4 + r;
        float mnew = fmaxf(m_run[idx], m);
        float fo = __expf(m_run[idx] - mnew);
        m_run[idx] = mnew;
        float ps = 0.f;
#pragma unroll
        for (int nf = 0; nf < 4; nf++) {
          float p = __expf(sfr[nf][r] - mnew);
          sfr[nf][r] = p;
          ps += p;
        }
#pragma unroll
        for (int off = 1; off < 16; off <<= 1) ps += __shfl_xor(ps, off);
        l_run[idx] = l_run[idx] * fo + ps;
#pragma unroll
        for (int df = 0; df < 4; df++) oacc[mf][df][r] *= fo;
      }
#pragma unroll
      for (int nf = 0; nf < 4; nf++)
#pragma unroll
        for (int r = 0; r < 4; r++)
          Ps[w][(mf * 16 + lg * 4 + r) * 64 + nf * 16 + lm] = f2bf(sfr[nf][r]);
    }
    asm volatile("" ::: "memory");
    s16x8 bv[4][2];
#pragma unroll
    for (int df = 0; df < 4; df++)
#pragma unroll
      for (int kk = 0; kk < 2; kk++)
        bv[df][kk] = *(const s16x8*)&Vt[(df * 16 + lm) * 64 + kk * 32 + lg * 8];
#pragma unroll
    for (int mf = 0; mf < 4; mf++) {
      s16x8 pa[2];
#pragma unroll
      for (int kk = 0; kk < 2; kk++)
        pa[kk] = *(const s16x8*)&Ps[w][(mf * 16 + lm) * 64 + kk * 32 + lg * 8];
#pragma unroll
      for (int df = 0; df < 4; df++)
#pragma unroll
        for (int kk = 0; kk < 2; kk++)
          oacc[mf][df] = __builtin_amdgcn_mfma_f32_16x16x32_bf16(pa[kk], bv[df][kk], oacc[mf][df], 0, 0, 0);
    }
  }

#pragma unroll
  for (int mf = 0; mf < 4; mf++)
#pragma unroll
    for (int df = 0; df < 4; df++)
#pragma unroll
      for (int r = 0; r < 4; r++) {
        int row = w * 64 + mf * 16 + lg * 4 + r;
        float val = oacc[mf][df][r] / l_run[mf * 4 + r];
        o[(tokbase + row) * 1024 + h * 64 + df * 16 + lm] = f2bf(val);
      }
}

// ---------------- residual + LayerNorm: wave-per-row, shfl-only ------------
__global__ __launch_bounds__(256)
void k_ln(u16* __restrict__ xb, const u16* __restrict__ tmp,
          const float* __restrict__ gam, const float* __restrict__ bet) {
  int t = blockIdx.x * 4 + (threadIdx.x >> 6);
  int lane = threadIdx.x & 63;
  size_t base = (size_t)t * DD + lane * 16;
  u16x8 a0 = *(const u16x8*)(xb + base);
  u16x8 a1 = *(const u16x8*)(xb + base + 8);
  u16x8 u0 = *(const u16x8*)(tmp + base);
  u16x8 u1 = *(const u16x8*)(tmp + base + 8);
  f32x4 v0, v1, v2, v3;
#pragma unroll
  for (int e = 0; e < 4; e++) {
    v0[e] = bf2f(a0[e]) + bf2f(u0[e]);
    v1[e] = bf2f(a0[4 + e]) + bf2f(u0[4 + e]);
    v2[e] = bf2f(a1[e]) + bf2f(u1[e]);
    v3[e] = bf2f(a1[4 + e]) + bf2f(u1[4 + e]);
  }
  float s = 0.f, s2 = 0.f;
#pragma unroll
  for (int e = 0; e < 4; e++) {
    s  += v0[e] + v1[e] + v2[e] + v3[e];
    s2 += v0[e]*v0[e] + v1[e]*v1[e] + v2[e]*v2[e] + v3[e]*v3[e];
  }
#pragma unroll
  for (int off = 32; off >= 1; off >>= 1) {
    s  += __shfl_xor(s, off);
    s2 += __shfl_xor(s2, off);
  }
  float mean = s * (1.f / 1024.f);
  float var = s2 * (1.f / 1024.f) - mean * mean;
  float rstd = rsqrtf(var + 1e-5f);
  const float* gp = gam + lane * 16;
  const float* bp = bet + lane * 16;
  f32x4 g0 = *(const f32x4*)(gp), g1 = *(const f32x4*)(gp + 4);
  f32x4 g2 = *(const f32x4*)(gp + 8), g3 = *(const f32x4*)(gp + 12);
  f32x4 b0 = *(const f32x4*)(bp), b1 = *(const f32x4*)(bp + 4);
  f32x4 b2 = *(const f32x4*)(bp + 8), b3 = *(const f32x4*)(bp + 12);
  u16x8 y0, y1;
#pragma unroll
  for (int e = 0; e < 4; e++) {
    y0[e]     = f2bf((v0[e] - mean) * rstd * g0[e] + b0[e]);
    y0[4 + e] = f2bf((v1[e] - mean) * rstd * g1[e] + b1[e]);
    y1[e]     = f2bf((v2[e] - mean) * rstd * g2[e] + b2[e]);
    y1[4 + e] = f2bf((v3[e] - mean) * rstd * g3[e] + b3[e]);
  }
  *(u16x8*)(xb + base) = y0;
  *(u16x8*)(xb + base + 8) = y1;
}

// ---------------- main-token dot precompute (x is bf16) ----------------
__global__ void k_main(const int* __restrict__ d_ids, const int* __restrict__ ut_len,
                       const u16* __restrict__ x, const float* __restrict__ decW,
                       float* __restrict__ md) {
  int b = blockIdx.x;
  int lane = threadIdx.x;   // 64
  int len = ut_len[d_ids[b]];
  const u16* xr = x + ((size_t)b * SS + (len - 1)) * DD;
  float acc[NCC];
#pragma unroll
  for (int c = 0; c < NCC; c++) acc[c] = 0.f;
  for (int d = lane; d < DD; d += 64) {
    float xv = bf2f(xr[d]);
#pragma unroll
    for (int c = 0; c < NCC; c++) acc[c] += xv * decW[(size_t)c * 2148 + 1024 + d];
  }
#pragma unroll
  for (int c = 0; c < NCC; c++) {
#pragma unroll
    for (int off = 32; off >= 1; off >>= 1) acc[c] += __shfl_xor(acc[c], off);
  }
  if (lane == 0) {
#pragma unroll
    for (int c = 0; c < NCC; c++) md[b * NCC + c] = acc[c];
  }
}

// ---------------- decoder (x is bf16) ----------------
__global__ __launch_bounds__(256)
void k_dec(const u16* __restrict__ x, const float* __restrict__ emo,
           const float* __restrict__ md, const float* __restrict__ decW,
           const float* __restrict__ decb, const int* __restrict__ d_ids,
           const int* __restrict__ ut_len, float* __restrict__ out) {
  int grp = threadIdx.x >> 6, lane = threadIdx.x & 63;
  int t = blockIdx.x * 4 + grp;
  int b = t / SS, s = t % SS;
  int len = ut_len[d_ids[b]];
  bool valid = s < len;
  float acc[NCC];
#pragma unroll
  for (int c = 0; c < NCC; c++) acc[c] = 0.f;
  if (valid) {
    const u16* xrow = x + (size_t)t * DD;
    for (int d = lane; d < DD; d += 64) {
      float xv = bf2f(xrow[d]);
#pragma unroll
      for (int c = 0; c < NCC; c++) acc[c] += xv * decW[(size_t)c * 2148 + d];
    }
  }
  {
    const float* er = emo + (size_t)t * GHH;
    for (int d = lane; d < GHH; d += 64) {
      float ev = er[d];
#pragma unroll
      for (int c = 0; c < NCC; c++) acc[c] += ev * decW[(size_t)c * 2148 + 2048 + d];
    }
  }
#pragma unroll
  for (int c = 0; c < NCC; c++) {
#pragma unroll
    for (int off = 32; off >= 1; off >>= 1) acc[c] += __shfl_xor(acc[c], off);
  }
  if (lane == 0) {
#pragma unroll
    for (int c = 0; c < NCC; c++) {
      float v = acc[c] + (valid ? md[b * NCC + c] : 0.f) + decb[c];
      out[(size_t)t * NCC + c] = v;
    }
  }
}

// ---------------- launch ----------------
extern "C" void kernel_launch(void* const* d_in, const int* in_sizes, int n_in,
                              void* d_out, int out_size, void* d_ws, size_t ws_size,
                              hipStream_t stream) {
  const int*   src    = (const int*)d_in[0];
  const float* em_seq = (const float*)d_in[1];
  const int*   d_ids  = (const int*)d_in[2];
  const int*   ut_len = (const int*)d_in[3];
  const float* emb    = (const float*)d_in[4];
  const float* Wqkv   = (const float*)d_in[5];
  const float* bqkv   = (const float*)d_in[6];
  const float* Wo     = (const float*)d_in[7];
  const float* bo     = (const float*)d_in[8];
  const float* W1     = (const float*)d_in[9];
  const float* b1     = (const float*)d_in[10];
  const float* W2     = (const float*)d_in[11];
  const float* b2     = (const float*)d_in[12];
  const float* ln1g   = (const float*)d_in[13];
  const float* ln1b   = (const float*)d_in[14];
  const float* ln2g   = (const float*)d_in[15];
  const float* ln2b   = (const float*)d_in[16];
  const float* gWih   = (const float*)d_in[17];
  const float* gWhh   = (const float*)d_in[18];
  const float* gbih   = (const float*)d_in[19];
  const float* gbhh   = (const float*)d_in[20];
  const float* decW   = (const float*)d_in[21];
  const float* decb   = (const float*)d_in[22];
  float* out = (float*)d_out;

  char* wsp = (char*)d_ws;
  auto take = [&](size_t n) { char* p = wsp; wsp += (n + 255) & ~(size_t)255; return p; };

  u16*   wall  = (u16*)take((size_t)LL * LS4 * 4 * 2);   // all-layer bf16 weights
  float* pe    = (float*)take((size_t)SS * DD * 4);
  u16*   xb    = (u16*)take((size_t)TT * DD * 2);
  u16*   big   = (u16*)take((size_t)TT * FFN * 2);
  u16*   ob    = (u16*)take((size_t)TT * DD * 2);
  u16*   tmp16 = (u16*)take((size_t)TT * DD * 2);
  float* emo   = (float*)take((size_t)BB * SS * GHH * 4);
  float* md    = (float*)take((size_t)BB * NCC * 4);

  (void)hipFuncSetAttribute((const void*)&k_gemm256<0>,
      hipFuncAttributeMaxDynamicSharedMemorySize, 131072);
  (void)hipFuncSetAttribute((const void*)&k_gemm256<1>,
      hipFuncAttributeMaxDynamicSharedMemorySize, 131072);

  // fused: GRU (blocks 0-63) + all-layer weight conversion (blocks 64+)
  k_gru_conv<<<BB + 2048, 640, 0, stream>>>(
      em_seq, gWih, gbih, gWhh, gbhh, emo,
      Wqkv, Wo, W1, W2, wall);

  // embedding + positional encoding
  k_pe<<<(SS * DD / 2 + 255) / 256, 256, 0, stream>>>(pe);
  k_embed<<<TT * DD / 4 / 256, 256, 0, stream>>>(src, emb, pe, xb);

  for (int l = 0; l < LL; ++l) {
    const u16* wqkvL = wall + (size_t)l * LS4 * 4;
    const u16* woL   = wqkvL + (size_t)QKV4 * 4;
    const u16* w1L   = wqkvL + (size_t)(QKV4 + WO4) * 4;
    const u16* w2L   = wqkvL + (size_t)(QKV4 + WO4 + W14) * 4;

    // QKV projection (reads xb = residual/LN stream)
    k_gemm256<0><<<(TT/256) * (3072/256), 512, 131072, stream>>>(
        xb, wqkvL, bqkv + (size_t)l * 3072, big, TT, 3072, 1024);
    // attention
    k_attn<<<dim3(HH, BB), 256, 0, stream>>>(big, ob);
    // output projection
    k_gemm256<0><<<(TT/256) * (1024/256), 512, 131072, stream>>>(
        ob, woL, bo + (size_t)l * 1024, tmp16, TT, 1024, 1024);
    // residual + LN1  (xb <- LN(xb + tmp16))
    k_ln<<<TT / 4, 256, 0, stream>>>(xb, tmp16, ln1g + (size_t)l * DD, ln1b + (size_t)l * DD);
    // FFN1 (relu)
    k_gemm256<1><<<(TT/256) * (4096/256), 512, 131072, stream>>>(
        xb, w1L, b1 + (size_t)l * 4096, big, TT, 4096, 1024);
    // FFN2
    k_gemm256<0><<<(TT/256) * (1024/256), 512, 131072, stream>>>(
        big, w2L, b2 + (size_t)l * 1024, tmp16, TT, 1024, 4096);
    // residual + LN2  (xb <- LN(xb + tmp16))
    k_ln<<<TT / 4, 256, 0, stream>>>(xb, tmp16, ln2g + (size_t)l * DD, ln2b + (size_t)l * DD);
  }

  // decoder
  k_main<<<BB, 64, 0, stream>>>(d_ids, ut_len, xb, decW, md);
  k_dec<<<TT / 4, 256, 0, stream>>>(xb, emo, md, decW, decb, d_ids, ut_len, out);
}

// Round 17
// 2236.611 us; speedup vs baseline: 1.1818x; 1.0074x over previous
//
#include <hip/hip_runtime.h>
#include <hip/hip_bf16.h>
#include <math.h>

// Problem constants
#define BB 64
#define SS 256
#define DD 1024
#define HH 16
#define FFN 4096
#define GHH 100
#define NCC 7
#define LL 4
#define TT (BB*SS)          // 16384 tokens
#define DHH 64

typedef unsigned short u16;
typedef unsigned int u32;
typedef __attribute__((ext_vector_type(4))) float f32x4;
typedef __attribute__((ext_vector_type(8))) short s16x8;
typedef __attribute__((ext_vector_type(4))) unsigned short u16x4;
typedef __attribute__((ext_vector_type(8))) unsigned short u16x8;

__device__ __forceinline__ u16 f2bf(float f) {
  union { float f; u32 u; } x; x.f = f;
  u32 r = x.u + 0x7FFFu + ((x.u >> 16) & 1u);
  return (u16)(r >> 16);
}
__device__ __forceinline__ float bf2f(u16 b) {
  union { u32 u; float f; } x; x.u = ((u32)b) << 16;
  return x.f;
}
__device__ __forceinline__ u32 pkbf(float a, float b) {
  return (u32)f2bf(a) | ((u32)f2bf(b) << 16);
}
__device__ __forceinline__ float lo16(u32 u) {
  union { u32 u; float f; } x; x.u = u << 16; return x.f;
}
__device__ __forceinline__ float hi16(u32 u) {
  union { u32 u; float f; } x; x.u = u & 0xffff0000u; return x.f;
}

// per-layer bf16 weight layout inside the big workspace block (f32x4 units)
#define LS4   3145728          // 12582912 elems / 4
#define QKV4  786432
#define WO4   262144
#define W14   1048576

// ---------------- GRU body (R10-proven; device fn for fusion) --------------
#define F7(X) X(0) X(1) X(2) X(3) X(4) X(5) X(6)
#define C12(X) X(0) X(1) X(2) X(3) X(4) X(5) X(6) X(7) X(8) X(9) X(10) X(11)

__device__ __forceinline__
void gru_body(const float* __restrict__ em, const float* __restrict__ Wih,
              const float* __restrict__ bih, const float* __restrict__ Whh,
              const float* __restrict__ bhh, float* __restrict__ emo, int b) {
  const int tid = threadIdx.x;
  const int iraw = tid / 6;
  const int sub = tid - iraw * 6;
  const int g = sub >> 1, half = sub & 1;
  const bool act = iraw < 100;
  const int i = act ? iraw : 99;
  const int grow = g * 100 + i;

  __shared__ __align__(16) float h[2][104];
  __shared__ float vals[400];
  __shared__ __align__(16) float emL[SS][8];
  __shared__ float emoL[16][100];

  const float* rowP = Whh + (size_t)grow * 100 + half * 50;
#define LW(q) u32 wa##q = pkbf(rowP[4*(q)], rowP[4*(q)+1]); \
              u32 wb##q = pkbf(rowP[4*(q)+2], rowP[4*(q)+3]); \
              asm volatile("" : "+v"(wa##q), "+v"(wb##q));
  C12(LW)
#undef LW
  u32 wt = pkbf(rowP[48], rowP[49]);
  asm volatile("" : "+v"(wt));

#define LI(f) float wi##f = Wih[grow * 7 + (f)];
  F7(LI)
#undef LI
  const float bhhv = bhh[grow];
  const float bihv = bih[grow];

  {
    const float* ebase = em + (size_t)b * SS * 7;
    for (int idx = tid; idx < SS * 7; idx += 640) {
      int ss = idx / 7, ff = idx - ss * 7;
      emL[ss][ff] = ebase[idx];
    }
  }
  if (tid < 104) { h[0][tid] = 0.f; h[1][tid] = 0.f; }
  __syncthreads();

  for (int s = 0; s < SS; ++s) {
    const float* hc = h[s & 1];
    float* hb_next = h[(s & 1) ^ 1];
    float xp = bihv;
#define MI(f) xp += wi##f * emL[s][f];
    F7(MI)
#undef MI
    const float* hbp = hc + half * 52;
    float a0 = 0.f, a1 = 0.f, a2 = 0.f, a3 = 0.f;
#define MC(q) { f32x4 hv = *(const f32x4*)(hbp + 4*(q)); \
    a0 += lo16(wa##q) * hv[0]; a1 += hi16(wa##q) * hv[1]; \
    a2 += lo16(wb##q) * hv[2]; a3 += hi16(wb##q) * hv[3]; }
    C12(MC)
#undef MC
    { a0 += lo16(wt) * hbp[48]; a1 += hi16(wt) * hbp[49]; }
    float a = (a0 + a1) + (a2 + a3);
    a += __shfl_xor(a, 1);
    if (act && half == 0) {
      if (g == 2) { vals[200 + i] = xp; vals[300 + i] = a + bhhv; }
      else        { vals[g * 100 + i] = xp + a + bhhv; }
    }
    __syncthreads();
    if (tid < 100) {
      int slot = tid + (tid >= 50 ? 2 : 0);
      float hold = hc[slot];
      float rr = 1.f / (1.f + __expf(-vals[tid]));
      float zz = 1.f / (1.f + __expf(-vals[100 + tid]));
      float nx = vals[200 + tid] + rr * vals[300 + tid];
      float e2 = __expf(-2.f * fabsf(nx));
      float th = (1.f - e2) / (1.f + e2);
      float nn = copysignf(th, nx);
      float hv = (1.f - zz) * nn + zz * hold;
      hb_next[slot] = hv;
      emoL[s & 15][tid] = hv;
    }
    __syncthreads();
    if ((s & 15) == 15) {
      float* dst = emo + ((size_t)b * SS + (s - 15)) * GHH;
      for (int idx = tid; idx < 16 * GHH; idx += 640)
        dst[idx] = (&emoL[0][0])[idx];
    }
  }
}

// ---------------- fused GRU + weight conversion + embed/PE -----------------
// Blocks 0..63: GRU (64 CUs, ~190us serial scan). Blocks 64+: grid-stride
// (1) fp32->bf16 convert of ALL 4 layers' weights, then (2) embedding + PE
// (PE computed inline, identical math to the old k_pe). Pure streaming,
// no barriers executed -> hidden under the GRU envelope (R16 measured ~140us
// of idle capacity on the non-GRU CUs).
__global__ __launch_bounds__(640, 1)
void k_gru_conv(const float* __restrict__ em, const float* __restrict__ Wih,
                const float* __restrict__ bih, const float* __restrict__ Whh,
                const float* __restrict__ bhh, float* __restrict__ emo,
                const float* __restrict__ Wqkv, const float* __restrict__ Wo,
                const float* __restrict__ W1, const float* __restrict__ W2,
                u16* __restrict__ wall,
                const int* __restrict__ src, const float* __restrict__ emb,
                u16* __restrict__ xb) {
  if ((int)blockIdx.x < BB) {
    gru_body(em, Wih, bih, Whh, bhh, emo, blockIdx.x);
    return;
  }
  const int idx0 = ((int)blockIdx.x - BB) * 640 + threadIdx.x;
  const int stride = ((int)gridDim.x - BB) * 640;
  // (1) weight conversion
  const int nTot4 = LL * LS4;                  // 12582912 f32x4 groups
  for (int i = idx0; i < nTot4; i += stride) {
    int l = i / LS4;
    int r = i - l * LS4;                        // f32x4 units within layer
    const float* s;
    if (r < QKV4)                 s = Wqkv + ((size_t)l * QKV4 + r) * 4;
    else if (r < QKV4 + WO4)      s = Wo   + ((size_t)l * WO4  + (r - QKV4)) * 4;
    else if (r < QKV4 + WO4 + W14) s = W1  + ((size_t)l * W14  + (r - QKV4 - WO4)) * 4;
    else                          s = W2   + ((size_t)l * W14  + (r - QKV4 - WO4 - W14)) * 4;
    f32x4 v = *(const f32x4*)s;
    u16x4 o;
    o[0] = f2bf(v[0]); o[1] = f2bf(v[1]); o[2] = f2bf(v[2]); o[3] = f2bf(v[3]);
    *(u16x4*)(wall + (size_t)i * 4) = o;
  }
  // (2) embedding + positional encoding (inline PE, same math as old k_pe)
  const float CPE = -9.210340371976184f / (float)DD;
  for (int i = idx0; i < TT * DD / 4; i += stride) {
    int t = i >> 8;                 // DD/4 = 256 groups per token row
    int d4 = (i & 255) * 4;
    int s = t & (SS - 1);
    int tok = src[t];
    f32x4 e = *(const f32x4*)(emb + (size_t)tok * DD + d4);
    float div0 = __expf((float)d4 * CPE);
    float div1 = __expf((float)(d4 + 2) * CPE);
    float a0 = (float)s * div0, a1 = (float)s * div1;
    float p0 = sinf(a0), p1 = cosf(a0), p2 = sinf(a1), p3 = cosf(a1);
    u16x4 o;
    o[0] = f2bf(e[0] * 32.0f + p0); o[1] = f2bf(e[1] * 32.0f + p1);
    o[2] = f2bf(e[2] * 32.0f + p2); o[3] = f2bf(e[3] * 32.0f + p3);
    *(u16x4*)(xb + (size_t)t * DD + d4) = o;
  }
}

// ---------------- 256x256 8-phase GEMM (T1+T2+T3+T4+T5) ----------------
#define MEMF asm volatile("" ::: "memory")
#define GBAR do { MEMF; __builtin_amdgcn_sched_barrier(0); __builtin_amdgcn_s_barrier(); __builtin_amdgcn_sched_barrier(0); MEMF; } while(0)
#define VMW4 asm volatile("s_waitcnt vmcnt(4)" ::: "memory")

#define STG(P, isB, h, l, buf, kt) \
  __builtin_amdgcn_global_load_lds( \
    (const __attribute__((address_space(1))) u32*)(P[h][l] + (kt)), \
    (__attribute__((address_space(3))) u32*)(smem + (buf)*65536 + (isB)*32768 + (h)*16384 + (l)*8192 + wid*1024), \
    16, 0, 0)

#define LDB(buf) do { \
  _Pragma("unroll") for (int nf = 0; nf < 4; nf++) \
  _Pragma("unroll") for (int kk = 0; kk < 2; kk++) { \
    int rel = (wn*64 + nf*16 + lm)*128 + kk*64 + lg*16; \
    bq[nf][kk] = *(const s16x8*)(smem + (buf)*65536 + 32768 + (rel ^ (((rel>>9)&1)<<5))); \
  } } while(0)

#define LDA(buf, q) do { \
  _Pragma("unroll") for (int ml = 0; ml < 2; ml++) \
  _Pragma("unroll") for (int kk = 0; kk < 2; kk++) { \
    int rel = (wm*128 + ((q)*2+ml)*16 + lm)*128 + kk*64 + lg*16; \
    aq[ml][kk] = *(const s16x8*)(smem + (buf)*65536 + (rel ^ (((rel>>9)&1)<<5))); \
  } } while(0)

#define MFMAQ(q) do { \
  __builtin_amdgcn_s_setprio(1); \
  _Pragma("unroll") for (int ml = 0; ml < 2; ml++) \
  _Pragma("unroll") for (int nf = 0; nf < 4; nf++) \
  _Pragma("unroll") for (int kk = 0; kk < 2; kk++) \
    acc[(q)*2+ml][nf] = __builtin_amdgcn_mfma_f32_16x16x32_bf16(aq[ml][kk], bq[nf][kk], acc[(q)*2+ml][nf], 0, 0, 0); \
  __builtin_amdgcn_s_setprio(0); \
} while(0)

template<int EPI>
__global__ __launch_bounds__(512, 2)
void k_gemm256(const u16* __restrict__ A, const u16* __restrict__ W,
               const float* __restrict__ bias, u16* __restrict__ C,
               int M, int N, int K) {
  extern __shared__ char smem[];
  const int tid = threadIdx.x;
  const int lane = tid & 63;
  const int wid = tid >> 6;
  const int lm = lane & 15, lg = lane >> 4;
  const int wm = wid >> 2, wn = wid & 3;

  const int NB = N >> 8;
  const int nwg = gridDim.x;
  const int bid = blockIdx.x;
  const int cpx = nwg >> 3;
  const int swzb = (bid & 7) * cpx + (bid >> 3);
  const int m0 = (swzb / NB) << 8;
  const int n0 = (swzb % NB) << 8;

  const u16* pA[2][2];
  const u16* pB[2][2];
#pragma unroll
  for (int h = 0; h < 2; h++)
#pragma unroll
    for (int l = 0; l < 2; l++) {
      int rel = h * 16384 + l * 8192 + tid * 16;
      int sb = rel ^ (((rel >> 9) & 1) << 5);
      int grow = sb >> 7;
      int gcol = (sb & 127) >> 1;
      pA[h][l] = A + (size_t)(m0 + grow) * K + gcol;
      pB[h][l] = W + (size_t)(n0 + grow) * K + gcol;
    }

  f32x4 acc[8][4];
#pragma unroll
  for (int i = 0; i < 8; i++)
#pragma unroll
    for (int j = 0; j < 4; j++) acc[i][j] = (f32x4){0.f, 0.f, 0.f, 0.f};

  s16x8 bq[4][2];
  s16x8 aq[2][2];

  const int NT = K >> 6;

  STG(pB,1,0,0,0,0); STG(pB,1,0,1,0,0); STG(pB,1,1,0,0,0); STG(pB,1,1,1,0,0);
  STG(pA,0,0,0,0,0); STG(pA,0,0,1,0,0); STG(pA,0,1,0,0,0); STG(pA,0,1,1,0,0);
  STG(pB,1,0,0,1,64); STG(pB,1,0,1,1,64); STG(pB,1,1,0,1,64); STG(pB,1,1,1,1,64);
  VMW4;
  GBAR;

  for (int i = 0; i < (NT >> 1); i++) {
    const int t1k = (2*i + 1) * 64;
    int t2 = 2*i + 2; if (t2 >= NT) t2 -= NT;
    int t3 = 2*i + 3; if (t3 >= NT) t3 -= NT;
    const int t2k = t2 * 64, t3k = t3 * 64;

    LDB(0); LDA(0,0);
    STG(pA,0,0,0,1,t1k); STG(pA,0,0,1,1,t1k);
    GBAR; MFMAQ(0); GBAR;
    LDA(0,1);
    STG(pA,0,1,0,1,t1k); STG(pA,0,1,1,1,t1k);
    STG(pB,1,0,0,0,t2k); STG(pB,1,0,1,0,t2k);
    GBAR; MFMAQ(1); GBAR;
    LDA(0,2);
    STG(pB,1,1,0,0,t2k); STG(pB,1,1,1,0,t2k);
    GBAR; MFMAQ(2); GBAR;
    LDA(0,3);
    GBAR; MFMAQ(3); VMW4; GBAR;
    LDB(1); LDA(1,0);
    STG(pA,0,0,0,0,t2k); STG(pA,0,0,1,0,t2k);
    GBAR; MFMAQ(0); GBAR;
    LDA(1,1);
    STG(pA,0,1,0,0,t2k); STG(pA,0,1,1,0,t2k);
    GBAR; MFMAQ(1); GBAR;
    LDA(1,2);
    STG(pB,1,0,0,1,t3k); STG(pB,1,0,1,1,t3k);
    GBAR; MFMAQ(2); GBAR;
    LDA(1,3);
    STG(pB,1,1,0,1,t3k); STG(pB,1,1,1,1,t3k);
    GBAR; MFMAQ(3); VMW4; GBAR;
  }

  float bn[4];
#pragma unroll
  for (int nf = 0; nf < 4; nf++) bn[nf] = bias[n0 + wn*64 + nf*16 + lm];
#pragma unroll
  for (int mf = 0; mf < 8; mf++)
#pragma unroll
    for (int nf = 0; nf < 4; nf++) {
      int col = n0 + wn*64 + nf*16 + lm;
#pragma unroll
      for (int r = 0; r < 4; r++) {
        int row = m0 + wm*128 + mf*16 + lg*4 + r;
        float v = acc[mf][nf][r] + bn[nf];
        if (EPI == 1) v = fmaxf(v, 0.f);
        C[(size_t)row * N + col] = f2bf(v);
      }
    }
}

// ---------------- fused causal attention (R10/R12-proven version) ----------
__global__ __launch_bounds__(256, 2)
void k_attn(const u16* __restrict__ qkv, u16* __restrict__ o) {
  const int h = blockIdx.x;     // 0..15
  const int b = blockIdx.y;     // 0..63
  const int lane = threadIdx.x & 63;
  const int w = threadIdx.x >> 6;    // q-block 0..3 (64 rows each)
  const int lm = lane & 15, lg = lane >> 4;

  __shared__ u16 Ks[64 * 64];       // [k_local][dh]
  __shared__ u16 Vt[64 * 64];       // [dh][k_local]
  __shared__ u16 Ps[4][64 * 64];    // per-wave P [q_local][k_local]

  const size_t tokbase = (size_t)b * SS;

  s16x8 aq[4][2];
#pragma unroll
  for (int mf = 0; mf < 4; mf++) {
    const u16* qrow = qkv + (tokbase + w * 64 + mf * 16 + lm) * 3072 + h * 64;
#pragma unroll
    for (int kk = 0; kk < 2; kk++)
      aq[mf][kk] = *(const s16x8*)(qrow + kk * 32 + lg * 8);
  }

  f32x4 zero = {0.f, 0.f, 0.f, 0.f};
  f32x4 oacc[4][4];
#pragma unroll
  for (int mf = 0; mf < 4; mf++)
#pragma unroll
    for (int df = 0; df < 4; df++) oacc[mf][df] = zero;
  float m_run[16], l_run[16];
#pragma unroll
  for (int r = 0; r < 16; r++) { m_run[r] = -3e38f; l_run[r] = 0.f; }

  for (int kb = 0; kb < 4; kb++) {
    __syncthreads();
    {
      int krow = threadIdx.x >> 2;
      int seg  = (threadIdx.x & 3) * 16;
      const u16* ksrc = qkv + (tokbase + kb * 64 + krow) * 3072 + 1024 + h * 64 + seg;
      s16x8 v0 = *(const s16x8*)(ksrc);
      s16x8 v1 = *(const s16x8*)(ksrc + 8);
      *(s16x8*)&Ks[krow * 64 + seg] = v0;
      *(s16x8*)&Ks[krow * 64 + seg + 8] = v1;
      const u16* vsrc = qkv + (tokbase + kb * 64 + krow) * 3072 + 2048 + h * 64 + seg;
      s16x8 w0 = *(const s16x8*)(vsrc);
      s16x8 w1 = *(const s16x8*)(vsrc + 8);
#pragma unroll
      for (int e = 0; e < 8; e++) {
        Vt[(seg + e) * 64 + krow]     = (u16)w0[e];
        Vt[(seg + 8 + e) * 64 + krow] = (u16)w1[e];
      }
    }
    __syncthreads();
    if (w < kb) continue;

    s16x8 bk[4][2];
#pragma unroll
    for (int nf = 0; nf < 4; nf++)
#pragma unroll
      for (int kk = 0; kk < 2; kk++)
        bk[nf][kk] = *(const s16x8*)&Ks[(nf * 16 + lm) * 64 + kk * 32 + lg * 8];

    const int colbase = kb * 64;
#pragma unroll
    for (int mf = 0; mf < 4; mf++) {
      f32x4 sfr[4];
#pragma unroll
      for (int nf = 0; nf < 4; nf++) {
        f32x4 acc = zero;
#pragma unroll
        for (int kk = 0; kk < 2; kk++)
          acc = __builtin_amdgcn_mfma_f32_16x16x32_bf16(aq[mf][kk], bk[nf][kk], acc, 0, 0, 0);
        sfr[nf] = acc;
      }
      const int rowbase = w * 64 + mf * 16 + lg * 4;
#pragma unroll
      for (int nf = 0; nf < 4; nf++) {
        int col = colbase + nf * 16 + lm;
#pragma unroll
        for (int r = 0; r < 4; r++) {
          float v = sfr[nf][r] * 0.125f;
          sfr[nf][r] = (col <= rowbase + r) ? v : -1e30f;
        }
      }
#pragma unroll
      for (int r = 0; r < 4; r++) {
        float m = fmaxf(fmaxf(sfr[0][r], sfr[1][r]), fmaxf(sfr[2][r], sfr[3][r]));
#pragma unroll
        for (int off = 1; off < 16; off <<= 1) m = fmaxf(m, __shfl_xor(m, off));
        int idx = mf * 4 + r;
        float mnew = fmaxf(m_run[idx], m);
        float fo = __expf(m_run[idx] - mnew);
        m_run[idx] = mnew;
        float ps = 0.f;
#pragma unroll
        for (int nf = 0; nf < 4; nf++) {
          float p = __expf(sfr[nf][r] - mnew);
          sfr[nf][r] = p;
          ps += p;
        }
#pragma unroll
        for (int off = 1; off < 16; off <<= 1) ps += __shfl_xor(ps, off);
        l_run[idx] = l_run[idx] * fo + ps;
#pragma unroll
        for (int df = 0; df < 4; df++) oacc[mf][df][r] *= fo;
      }
#pragma unroll
      for (int nf = 0; nf < 4; nf++)
#pragma unroll
        for (int r = 0; r < 4; r++)
          Ps[w][(mf * 16 + lg * 4 + r) * 64 + nf * 16 + lm] = f2bf(sfr[nf][r]);
    }
    asm volatile("" ::: "memory");
    s16x8 bv[4][2];
#pragma unroll
    for (int df = 0; df < 4; df++)
#pragma unroll
      for (int kk = 0; kk < 2; kk++)
        bv[df][kk] = *(const s16x8*)&Vt[(df * 16 + lm) * 64 + kk * 32 + lg * 8];
#pragma unroll
    for (int mf = 0; mf < 4; mf++) {
      s16x8 pa[2];
#pragma unroll
      for (int kk = 0; kk < 2; kk++)
        pa[kk] = *(const s16x8*)&Ps[w][(mf * 16 + lm) * 64 + kk * 32 + lg * 8];
#pragma unroll
      for (int df = 0; df < 4; df++)
#pragma unroll
        for (int kk = 0; kk < 2; kk++)
          oacc[mf][df] = __builtin_amdgcn_mfma_f32_16x16x32_bf16(pa[kk], bv[df][kk], oacc[mf][df], 0, 0, 0);
    }
  }

#pragma unroll
  for (int mf = 0; mf < 4; mf++)
#pragma unroll
    for (int df = 0; df < 4; df++)
#pragma unroll
      for (int r = 0; r < 4; r++) {
        int row = w * 64 + mf * 16 + lg * 4 + r;
        float val = oacc[mf][df][r] / l_run[mf * 4 + r];
        o[(tokbase + row) * 1024 + h * 64 + df * 16 + lm] = f2bf(val);
      }
}

// ---------------- residual + LayerNorm: wave-per-row, shfl-only ------------
__global__ __launch_bounds__(256)
void k_ln(u16* __restrict__ xb, const u16* __restrict__ tmp,
          const float* __restrict__ gam, const float* __restrict__ bet) {
  int t = blockIdx.x * 4 + (threadIdx.x >> 6);
  int lane = threadIdx.x & 63;
  size_t base = (size_t)t * DD + lane * 16;
  u16x8 a0 = *(const u16x8*)(xb + base);
  u16x8 a1 = *(const u16x8*)(xb + base + 8);
  u16x8 u0 = *(const u16x8*)(tmp + base);
  u16x8 u1 = *(const u16x8*)(tmp + base + 8);
  f32x4 v0, v1, v2, v3;
#pragma unroll
  for (int e = 0; e < 4; e++) {
    v0[e] = bf2f(a0[e]) + bf2f(u0[e]);
    v1[e] = bf2f(a0[4 + e]) + bf2f(u0[4 + e]);
    v2[e] = bf2f(a1[e]) + bf2f(u1[e]);
    v3[e] = bf2f(a1[4 + e]) + bf2f(u1[4 + e]);
  }
  float s = 0.f, s2 = 0.f;
#pragma unroll
  for (int e = 0; e < 4; e++) {
    s  += v0[e] + v1[e] + v2[e] + v3[e];
    s2 += v0[e]*v0[e] + v1[e]*v1[e] + v2[e]*v2[e] + v3[e]*v3[e];
  }
#pragma unroll
  for (int off = 32; off >= 1; off >>= 1) {
    s  += __shfl_xor(s, off);
    s2 += __shfl_xor(s2, off);
  }
  float mean = s * (1.f / 1024.f);
  float var = s2 * (1.f / 1024.f) - mean * mean;
  float rstd = rsqrtf(var + 1e-5f);
  const float* gp = gam + lane * 16;
  const float* bp = bet + lane * 16;
  f32x4 g0 = *(const f32x4*)(gp), g1 = *(const f32x4*)(gp + 4);
  f32x4 g2 = *(const f32x4*)(gp + 8), g3 = *(const f32x4*)(gp + 12);
  f32x4 b0 = *(const f32x4*)(bp), b1 = *(const f32x4*)(bp + 4);
  f32x4 b2 = *(const f32x4*)(bp + 8), b3 = *(const f32x4*)(bp + 12);
  u16x8 y0, y1;
#pragma unroll
  for (int e = 0; e < 4; e++) {
    y0[e]     = f2bf((v0[e] - mean) * rstd * g0[e] + b0[e]);
    y0[4 + e] = f2bf((v1[e] - mean) * rstd * g1[e] + b1[e]);
    y1[e]     = f2bf((v2[e] - mean) * rstd * g2[e] + b2[e]);
    y1[4 + e] = f2bf((v3[e] - mean) * rstd * g3[e] + b3[e]);
  }
  *(u16x8*)(xb + base) = y0;
  *(u16x8*)(xb + base + 8) = y1;
}

// ---------------- main-token dot precompute (x is bf16) ----------------
__global__ void k_main(const int* __restrict__ d_ids, const int* __restrict__ ut_len,
                       const u16* __restrict__ x, const float* __restrict__ decW,
                       float* __restrict__ md) {
  int b = blockIdx.x;
  int lane = threadIdx.x;   // 64
  int len = ut_len[d_ids[b]];
  const u16* xr = x + ((size_t)b * SS + (len - 1)) * DD;
  float acc[NCC];
#pragma unroll
  for (int c = 0; c < NCC; c++) acc[c] = 0.f;
  for (int d = lane; d < DD; d += 64) {
    float xv = bf2f(xr[d]);
#pragma unroll
    for (int c = 0; c < NCC; c++) acc[c] += xv * decW[(size_t)c * 2148 + 1024 + d];
  }
#pragma unroll
  for (int c = 0; c < NCC; c++) {
#pragma unroll
    for (int off = 32; off >= 1; off >>= 1) acc[c] += __shfl_xor(acc[c], off);
  }
  if (lane == 0) {
#pragma unroll
    for (int c = 0; c < NCC; c++) md[b * NCC + c] = acc[c];
  }
}

// ---------------- decoder (x is bf16) ----------------
__global__ __launch_bounds__(256)
void k_dec(const u16* __restrict__ x, const float* __restrict__ emo,
           const float* __restrict__ md, const float* __restrict__ decW,
           const float* __restrict__ decb, const int* __restrict__ d_ids,
           const int* __restrict__ ut_len, float* __restrict__ out) {
  int grp = threadIdx.x >> 6, lane = threadIdx.x & 63;
  int t = blockIdx.x * 4 + grp;
  int b = t / SS, s = t % SS;
  int len = ut_len[d_ids[b]];
  bool valid = s < len;
  float acc[NCC];
#pragma unroll
  for (int c = 0; c < NCC; c++) acc[c] = 0.f;
  if (valid) {
    const u16* xrow = x + (size_t)t * DD;
    for (int d = lane; d < DD; d += 64) {
      float xv = bf2f(xrow[d]);
#pragma unroll
      for (int c = 0; c < NCC; c++) acc[c] += xv * decW[(size_t)c * 2148 + d];
    }
  }
  {
    const float* er = emo + (size_t)t * GHH;
    for (int d = lane; d < GHH; d += 64) {
      float ev = er[d];
#pragma unroll
      for (int c = 0; c < NCC; c++) acc[c] += ev * decW[(size_t)c * 2148 + 2048 + d];
    }
  }
#pragma unroll
  for (int c = 0; c < NCC; c++) {
#pragma unroll
    for (int off = 32; off >= 1; off >>= 1) acc[c] += __shfl_xor(acc[c], off);
  }
  if (lane == 0) {
#pragma unroll
    for (int c = 0; c < NCC; c++) {
      float v = acc[c] + (valid ? md[b * NCC + c] : 0.f) + decb[c];
      out[(size_t)t * NCC + c] = v;
    }
  }
}

// ---------------- launch ----------------
extern "C" void kernel_launch(void* const* d_in, const int* in_sizes, int n_in,
                              void* d_out, int out_size, void* d_ws, size_t ws_size,
                              hipStream_t stream) {
  const int*   src    = (const int*)d_in[0];
  const float* em_seq = (const float*)d_in[1];
  const int*   d_ids  = (const int*)d_in[2];
  const int*   ut_len = (const int*)d_in[3];
  const float* emb    = (const float*)d_in[4];
  const float* Wqkv   = (const float*)d_in[5];
  const float* bqkv   = (const float*)d_in[6];
  const float* Wo     = (const float*)d_in[7];
  const float* bo     = (const float*)d_in[8];
  const float* W1     = (const float*)d_in[9];
  const float* b1     = (const float*)d_in[10];
  const float* W2     = (const float*)d_in[11];
  const float* b2     = (const float*)d_in[12];
  const float* ln1g   = (const float*)d_in[13];
  const float* ln1b   = (const float*)d_in[14];
  const float* ln2g   = (const float*)d_in[15];
  const float* ln2b   = (const float*)d_in[16];
  const float* gWih   = (const float*)d_in[17];
  const float* gWhh   = (const float*)d_in[18];
  const float* gbih   = (const float*)d_in[19];
  const float* gbhh   = (const float*)d_in[20];
  const float* decW   = (const float*)d_in[21];
  const float* decb   = (const float*)d_in[22];
  float* out = (float*)d_out;

  char* wsp = (char*)d_ws;
  auto take = [&](size_t n) { char* p = wsp; wsp += (n + 255) & ~(size_t)255; return p; };

  u16*   wall  = (u16*)take((size_t)LL * LS4 * 4 * 2);   // all-layer bf16 weights
  u16*   xb    = (u16*)take((size_t)TT * DD * 2);
  u16*   big   = (u16*)take((size_t)TT * FFN * 2);
  u16*   ob    = (u16*)take((size_t)TT * DD * 2);
  u16*   tmp16 = (u16*)take((size_t)TT * DD * 2);
  float* emo   = (float*)take((size_t)BB * SS * GHH * 4);
  float* md    = (float*)take((size_t)BB * NCC * 4);

  (void)hipFuncSetAttribute((const void*)&k_gemm256<0>,
      hipFuncAttributeMaxDynamicSharedMemorySize, 131072);
  (void)hipFuncSetAttribute((const void*)&k_gemm256<1>,
      hipFuncAttributeMaxDynamicSharedMemorySize, 131072);

  // fused: GRU (blocks 0-63) + weight conversion + embed/PE (blocks 64+)
  k_gru_conv<<<BB + 2048, 640, 0, stream>>>(
      em_seq, gWih, gbih, gWhh, gbhh, emo,
      Wqkv, Wo, W1, W2, wall, src, emb, xb);

  for (int l = 0; l < LL; ++l) {
    const u16* wqkvL = wall + (size_t)l * LS4 * 4;
    const u16* woL   = wqkvL + (size_t)QKV4 * 4;
    const u16* w1L   = wqkvL + (size_t)(QKV4 + WO4) * 4;
    const u16* w2L   = wqkvL + (size_t)(QKV4 + WO4 + W14) * 4;

    // QKV projection (reads xb = residual/LN stream)
    k_gemm256<0><<<(TT/256) * (3072/256), 512, 131072, stream>>>(
        xb, wqkvL, bqkv + (size_t)l * 3072, big, TT, 3072, 1024);
    // attention
    k_attn<<<dim3(HH, BB), 256, 0, stream>>>(big, ob);
    // output projection
    k_gemm256<0><<<(TT/256) * (1024/256), 512, 131072, stream>>>(
        ob, woL, bo + (size_t)l * 1024, tmp16, TT, 1024, 1024);
    // residual + LN1  (xb <- LN(xb + tmp16))
    k_ln<<<TT / 4, 256, 0, stream>>>(xb, tmp16, ln1g + (size_t)l * DD, ln1b + (size_t)l * DD);
    // FFN1 (relu)
    k_gemm256<1><<<(TT/256) * (4096/256), 512, 131072, stream>>>(
        xb, w1L, b1 + (size_t)l * 4096, big, TT, 4096, 1024);
    // FFN2
    k_gemm256<0><<<(TT/256) * (1024/256), 512, 131072, stream>>>(
        big, w2L, b2 + (size_t)l * 1024, tmp16, TT, 1024, 4096);
    // residual + LN2  (xb <- LN(xb + tmp16))
    k_ln<<<TT / 4, 256, 0, stream>>>(xb, tmp16, ln2g + (size_t)l * DD, ln2b + (size_t)l * DD);
  }

  // decoder
  k_main<<<BB, 64, 0, stream>>>(d_ids, ut_len, xb, decW, md);
  k_dec<<<TT / 4, 256, 0, stream>>>(xb, emo, md, decW, decb, d_ids, ut_len, out);
}